// Round 5
// baseline (176.161 us; speedup 1.0000x reference)
//
#include <hip/hip_runtime.h>
#include <hip/hip_bf16.h>

#define B_    8
#define CIN   256
#define COUT  768
#define G_    24
#define PW    40         // padded row width (16B-aligned rows)
#define PLANE 1440       // 40*36
#define EPS_  1e-5f
#define REP_GEMM 2
#define REP_ATTN 2

typedef float f32x4 __attribute__((ext_vector_type(4)));
typedef short s16x8 __attribute__((ext_vector_type(8)));
typedef unsigned short ushort_t;
typedef unsigned short u16x8 __attribute__((ext_vector_type(8)));
typedef unsigned long long ull_t;

static __device__ __forceinline__ ushort_t f2bf(float f) {
    union { float f; unsigned u; } a; a.f = f;
    const unsigned u = a.u;
    const unsigned r = u + 0x7FFFu + ((u >> 16) & 1u);
    return (ushort_t)(r >> 16);
}
static __device__ __forceinline__ float bf2f(ushort_t h) {
    union { unsigned u; float f; } a; a.u = ((unsigned)h) << 16; return a.f;
}

// ---------------- Kernel 0: prep (Xt transpose+cvt, Wt cvt) ----------------
__launch_bounds__(256)
__global__ void prep(const float* __restrict__ x, const float* __restrict__ w,
                     ushort_t* __restrict__ Xt, ushort_t* __restrict__ Wt) {
    const int z = blockIdx.x;
    const int t = threadIdx.x;
    if (z < 2048) {
        __shared__ ushort_t tile[32][33];
        const int b  = z >> 8, rem = z & 255;
        const int k0 = (rem >> 5) * 32, n0 = (rem & 31) * 32;
        const int kk = t >> 5, nn = t & 31;
        #pragma unroll
        for (int it = 0; it < 4; ++it) {
            const int kr = kk + it * 8;
            tile[kr][nn] = f2bf(x[((size_t)(b * 256 + k0 + kr)) * 1024 + n0 + nn]);
        }
        __syncthreads();
        const int kk2 = t & 31, nb = t >> 5;
        #pragma unroll
        for (int it = 0; it < 4; ++it) {
            const int nr = nb + it * 8;
            Xt[((size_t)(b * 1024 + n0 + nr)) * 256 + k0 + kk2] = tile[kk2][nr];
        }
    } else {
        const int idx = (z - 2048) * 256 + t;   // 768*256
        Wt[idx] = f2bf(w[idx]);
    }
}

// ---------------- Kernel 1: bf16 MFMA GEMM -> padded bf16 attn + rowAgg ------
__launch_bounds__(256)
__global__ void conv_gemm(const ushort_t* __restrict__ Wt, const ushort_t* __restrict__ Xt,
                          const float* __restrict__ bias, ushort_t* __restrict__ attn,
                          float* __restrict__ rowAgg) {
    const int t = threadIdx.x;
    const int wv = t >> 6, lane = t & 63;
    const int q = lane >> 4, l15 = lane & 15;
    const int m0 = blockIdx.y * 64;
    const int mw = wv * 16;
    const int n_t = blockIdx.x * 64;
    const int b = n_t >> 10, nl0 = n_t & 1023;
    const int y0 = nl0 >> 5;

    __shared__ ushort_t Ct[64][2][44];
    __shared__ float red[128][11];

    const ushort_t* aP = Wt + (size_t)(m0 + mw + l15) * 256 + q * 8;
    const ushort_t* bP = Xt + (size_t)(b * 1024 + nl0 + l15) * 256 + q * 8;

    #pragma unroll 1
    for (int rep = 0; rep < REP_GEMM; ++rep) {
        __syncthreads();                      // protect LDS reuse across reps
        f32x4 acc[4] = {{0,0,0,0},{0,0,0,0},{0,0,0,0},{0,0,0,0}};
        #pragma unroll
        for (int k0 = 0; k0 < 256; k0 += 32) {
            const s16x8 a  = *(const s16x8*)(aP + k0);
            const s16x8 b0 = *(const s16x8*)(bP + k0);
            const s16x8 b1 = *(const s16x8*)(bP + 16 * 256 + k0);
            const s16x8 b2 = *(const s16x8*)(bP + 32 * 256 + k0);
            const s16x8 b3 = *(const s16x8*)(bP + 48 * 256 + k0);
            acc[0] = __builtin_amdgcn_mfma_f32_16x16x32_bf16(a, b0, acc[0], 0, 0, 0);
            acc[1] = __builtin_amdgcn_mfma_f32_16x16x32_bf16(a, b1, acc[1], 0, 0, 0);
            acc[2] = __builtin_amdgcn_mfma_f32_16x16x32_bf16(a, b2, acc[2], 0, 0, 0);
            acc[3] = __builtin_amdgcn_mfma_f32_16x16x32_bf16(a, b3, acc[3], 0, 0, 0);
        }

        float bb[4];
        #pragma unroll
        for (int r = 0; r < 4; ++r) bb[r] = bias[m0 + mw + q * 4 + r];
        #pragma unroll
        for (int j = 0; j < 4; ++j) {
            const int yy = j >> 1, xx = (j & 1) * 16 + l15;
            #pragma unroll
            for (int r = 0; r < 4; ++r)
                Ct[mw + q * 4 + r][yy][2 + xx] = f2bf(acc[j][r] + bb[r]);
        }
        #pragma unroll
        for (int it = 0; it < 2; ++it) {
            const int id = it * 256 + t;
            const int m = id >> 3, yy = (id >> 2) & 1, pos = id & 3;
            const int us = (pos == 0) ? 0 : (32 + 2 * pos);
            *(unsigned*)&Ct[m][yy][us] = 0u;
        }
        __syncthreads();

        ushort_t* pb = attn + ((size_t)(b * COUT + m0)) * PLANE;
        #pragma unroll
        for (int it = 0; it < 5; ++it) {
            const int id = it * 256 + t;
            const int m = id / 20, rem = id % 20, yy = rem / 10, s = rem % 10;
            const ull_t v = *(const ull_t*)&Ct[m][yy][s * 4];
            *(ull_t*)(pb + (size_t)m * PLANE + (y0 + yy + 2) * PW + s * 4) = v;
        }
        if (y0 == 0 || y0 == 30) {
            const int rowA = (y0 == 0) ? 0 : 34;
            #pragma unroll
            for (int it = 0; it < 5; ++it) {
                const int id = it * 256 + t;
                const int m = id / 20, rem = id % 20, yy = rem / 10, s = rem % 10;
                *(ull_t*)(pb + (size_t)m * PLANE + (rowA + yy) * PW + s * 4) = 0ull;
            }
        }

        if (t < 128) {
            const int gi = t >> 6, yy = (t >> 5) & 1, c = t & 31;
            const int m = gi * 32 + c;
            float lin = 0.f, sq = 0.f, e0 = 0.f, e1 = 0.f, e30 = 0.f, e31 = 0.f;
            #pragma unroll
            for (int u = 0; u < 9; ++u) {
                const ull_t vv = *(const ull_t*)&Ct[m][yy][u * 4];
                const unsigned lo = (unsigned)vv, hi = (unsigned)(vv >> 32);
                union { unsigned u; float f; } f0, f1, f2, f3;
                f0.u = lo << 16; f1.u = lo & 0xffff0000u;
                f2.u = hi << 16; f3.u = hi & 0xffff0000u;
                lin += (f0.f + f1.f) + (f2.f + f3.f);
                sq  += (f0.f * f0.f + f1.f * f1.f) + (f2.f * f2.f + f3.f * f3.f);
                if (u == 0) { e0 = f2.f; e1 = f3.f; }
                if (u == 8) { e30 = f0.f; e31 = f1.f; }
            }
            red[t][0] = lin; red[t][1] = sq;
            red[t][2] = e0;  red[t][3] = e0 * e0;
            red[t][4] = e1;  red[t][5] = e1 * e1;
            red[t][6] = e30; red[t][7] = e30 * e30;
            red[t][8] = e31; red[t][9] = e31 * e31;
        }
        __syncthreads();
        if (t < 40) {
            const int s = t % 10, gy = t / 10;
            const int gi = gy >> 1, yy = gy & 1;
            float sum = 0.f;
            #pragma unroll
            for (int c = 0; c < 32; ++c) sum += red[gi * 64 + yy * 32 + c][s];
            const int g = blockIdx.y * 2 + gi;
            rowAgg[(((size_t)b * G_ + g) * 32 + (y0 + yy)) * 10 + s] = sum;
        }
    }
}

// ---------------- Kernel 2: tiny stats finalize ----------------
__launch_bounds__(64)
__global__ void gnfin(const float* __restrict__ rowAgg,
                      float* __restrict__ meanArr, float* __restrict__ rstdArr) {
    const int bg = blockIdx.x;
    const int t = threadIdx.x;
    __shared__ float rp[32][5], rp2[32][5];
    if (t < 32) {
        const float* a = rowAgg + ((size_t)bg * 32 + t) * 10;
        const float S = a[0], Sq = a[1];
        const float e0 = a[2], q0 = a[3], e1 = a[4], q1 = a[5];
        const float e30 = a[6], q30 = a[7], e31 = a[8], q31 = a[9];
        rp[t][0] = S - e30 - e31; rp[t][1] = S - e31; rp[t][2] = S;
        rp[t][3] = S - e0;        rp[t][4] = S - e0 - e1;
        rp2[t][0] = Sq - q30 - q31; rp2[t][1] = Sq - q31; rp2[t][2] = Sq;
        rp2[t][3] = Sq - q0;        rp2[t][4] = Sq - q0 - q1;
    }
    __syncthreads();
    if (t < 25) {
        const int kw = t % 5, kh = t / 5;
        float cs = 0.f, cs2 = 0.f;
        #pragma unroll
        for (int yy = 0; yy < 32; ++yy) { cs += rp[yy][kw]; cs2 += rp2[yy][kw]; }
        if (kh == 0)      { cs -= rp[30][kw] + rp[31][kw]; cs2 -= rp2[30][kw] + rp2[31][kw]; }
        else if (kh == 1) { cs -= rp[31][kw];              cs2 -= rp2[31][kw]; }
        else if (kh == 3) { cs -= rp[0][kw];               cs2 -= rp2[0][kw]; }
        else if (kh == 4) { cs -= rp[0][kw] + rp[1][kw];   cs2 -= rp2[0][kw] + rp2[1][kw]; }
        const float inv_n = 1.f / 32768.f;
        const float mean = cs * inv_n;
        const float var  = cs2 * inv_n - mean * mean;
        meanArr[bg * 25 + t] = mean;
        rstdArr[bg * 25 + t] = rsqrtf(var + EPS_);
    }
}

// ---------------- Kernel 3: local attention, 512 blocks x 128 threads --------
__launch_bounds__(128, 2)
__global__ void local_attn(const ushort_t* __restrict__ attn,
                           const float* __restrict__ meanArr, const float* __restrict__ rstdArr,
                           const float* __restrict__ gn_w, const float* __restrict__ gn_b,
                           float* __restrict__ out) {
    const int blk = blockIdx.x;          // 512
    const int b = blk >> 6;
    const int n = (blk >> 3) & 7;
    const int slab = blk & 7;            // 8 slabs of 4 rows
    const int i0 = slab * 4;
    const int t = threadIdx.x;
    const int r = t >> 5, j = t & 31;

    __shared__ float Ks[2][320];
    __shared__ float Qs[2][320];
    __shared__ float Vs[2][640];
    __shared__ float s_rq[25], s_mq[25], s_rk[25], s_ck[25], s_rv[25], s_cv[25];
    __shared__ float s_gw[96], s_gb[96];

    if (t < 25) {
        const int gk = (b * G_ + n * 3) * 25 + t;
        const float mK = meanArr[gk],      rK = rstdArr[gk];
        const float mQ = meanArr[gk + 25], rQ = rstdArr[gk + 25];
        const float mV = meanArr[gk + 50], rV = rstdArr[gk + 50];
        s_rk[t] = rK; s_ck[t] = mK * rK;
        s_rq[t] = rQ; s_mq[t] = mQ * rQ;
        s_rv[t] = rV; s_cv[t] = mV * rV;
    }
    if (t < 96) { s_gw[t] = gn_w[n * 96 + t]; s_gb[t] = gn_b[n * 96 + t]; }
    __syncthreads();

    float rq[25]; float cQ = 0.f;
    #pragma unroll
    for (int p = 0; p < 25; ++p) { rq[p] = s_rq[p]; cQ += s_mq[p]; }

    // staging: padded rows i0..i0+7 -> 320 elems/plane; 40 stagers/plane x u16x8
    const ushort_t* aB = attn + (size_t)(b * COUT + n * 96) * PLANE + i0 * PW;
    const bool stg = (t < 80);
    const int sp = (t < 40) ? 0 : 1;
    const int eo = ((t < 40) ? t : (t - 40)) * 8;
    const int base = r * PW + j;

    #pragma unroll 1
    for (int rep = 0; rep < REP_ATTN; ++rep) {
        u16x8 vr = {0, 0, 0, 0, 0, 0, 0, 0};
        if (stg) vr = *(const u16x8*)(aB + (size_t)(sp * 32) * PLANE + eo);

        float sal[25];
        #pragma unroll
        for (int p = 0; p < 25; ++p) sal[p] = 0.f;
        float sumQ2 = 0.f, sumQB = 0.f;

        for (int ch = 0; ch < 32; ++ch) {
            const int buf = ch & 1;
            if (stg) {
                f32x4 lo = { bf2f(vr[0]), bf2f(vr[1]), bf2f(vr[2]), bf2f(vr[3]) };
                f32x4 hi = { bf2f(vr[4]), bf2f(vr[5]), bf2f(vr[6]), bf2f(vr[7]) };
                if (sp == 0) { *(f32x4*)&Ks[buf][eo] = lo; *(f32x4*)&Ks[buf][eo + 4] = hi; }
                else         { *(f32x4*)&Qs[buf][eo] = lo; *(f32x4*)&Qs[buf][eo + 4] = hi; }
            }
            __syncthreads();
            if (stg) {
                if (ch < 31) vr = *(const u16x8*)(aB + (size_t)(ch + 1 + sp * 32) * PLANE + eo);
                else         vr = *(const u16x8*)(aB + (size_t)(64 + sp) * PLANE + eo);
            }
            const float* qb = &Qs[buf][base];
            const float* kb = &Ks[buf][base];
            float qa0 = 0.f, qa1 = 0.f, qa2 = 0.f, qa3 = 0.f, qa4 = 0.f;
            #pragma unroll
            for (int kw = 0; kw < 5; ++kw) {
                qa0 += rq[0 * 5 + kw] * qb[0 * PW + kw];
                qa1 += rq[1 * 5 + kw] * qb[1 * PW + kw];
                qa2 += rq[2 * 5 + kw] * qb[2 * PW + kw];
                qa3 += rq[3 * 5 + kw] * qb[3 * PW + kw];
                qa4 += rq[4 * 5 + kw] * qb[4 * PW + kw];
            }
            const float qa = (qa0 + qa1) + (qa2 + qa3) + qa4;
            const float qk  = s_gw[32 + ch] * ((qa - cQ) * 0.04f) + s_gb[32 + ch];
            const float qk2 = qk * s_gw[ch];
            sumQ2 += qk2; sumQB += qk * s_gb[ch];
            #pragma unroll
            for (int kh = 0; kh < 5; ++kh)
                #pragma unroll
                for (int kw = 0; kw < 5; ++kw)
                    sal[kh * 5 + kw] += qk2 * kb[kh * PW + kw];
        }

        #pragma unroll
        for (int p = 0; p < 25; ++p) sal[p] = s_rk[p] * sal[p] - s_ck[p] * sumQ2 + sumQB;

        const float scale = 0.17677669529663687f;
        float mmax = -3.4e38f;
        #pragma unroll
        for (int p = 0; p < 25; ++p) { sal[p] *= scale; mmax = fmaxf(mmax, sal[p]); }
        float ssum = 0.f;
        #pragma unroll
        for (int p = 0; p < 25; ++p) { sal[p] = __expf(sal[p] - mmax); ssum += sal[p]; }
        const float rs = 1.f / ssum;
        float w2[25]; float cV2 = 0.f;
        #pragma unroll
        for (int p = 0; p < 25; ++p) {
            const float m = sal[p] * rs;
            w2[p] = m * s_rv[p];
            cV2 += m * s_cv[p];
        }

        for (int vi = 0; vi < 16; ++vi) {
            const int buf = vi & 1;
            if (stg) {
                f32x4 lo = { bf2f(vr[0]), bf2f(vr[1]), bf2f(vr[2]), bf2f(vr[3]) };
                f32x4 hi = { bf2f(vr[4]), bf2f(vr[5]), bf2f(vr[6]), bf2f(vr[7]) };
                *(f32x4*)&Vs[buf][sp * 320 + eo] = lo;
                *(f32x4*)&Vs[buf][sp * 320 + eo + 4] = hi;
            }
            __syncthreads();
            if (stg) {
                if (vi < 15) vr = *(const u16x8*)(aB + (size_t)(64 + 2 * (vi + 1) + sp) * PLANE + eo);
                else         vr = *(const u16x8*)(aB + (size_t)(sp * 32) * PLANE + eo);  // rep2 K/Q ch0
            }
            #pragma unroll
            for (int h = 0; h < 2; ++h) {
                const float* vb = &Vs[buf][h * 320 + base];
                float a0 = 0.f, a1 = 0.f, a2 = 0.f, a3 = 0.f, a4 = 0.f;
                #pragma unroll
                for (int kw = 0; kw < 5; ++kw) {
                    a0 += w2[0 * 5 + kw] * vb[0 * PW + kw];
                    a1 += w2[1 * 5 + kw] * vb[1 * PW + kw];
                    a2 += w2[2 * 5 + kw] * vb[2 * PW + kw];
                    a3 += w2[3 * 5 + kw] * vb[3 * PW + kw];
                    a4 += w2[4 * 5 + kw] * vb[4 * PW + kw];
                }
                const float acc = (a0 + a1) + (a2 + a3) + a4;
                const int v = vi * 2 + h;
                out[((size_t)(b * 256 + n * 32 + v) * 32 + (i0 + r)) * 32 + j] =
                    s_gw[64 + v] * acc + (s_gb[64 + v] - s_gw[64 + v] * cV2);
            }
        }
        __syncthreads();   // protect Ks/Qs reuse across reps
    }
}

extern "C" void kernel_launch(void* const* d_in, const int* in_sizes, int n_in,
                              void* d_out, int out_size, void* d_ws, size_t ws_size,
                              hipStream_t stream) {
    const float* x      = (const float*)d_in[0];
    const float* conv_w = (const float*)d_in[1];
    const float* conv_b = (const float*)d_in[2];
    const float* gn_w   = (const float*)d_in[3];
    const float* gn_b   = (const float*)d_in[4];
    float* out = (float*)d_out;

    ushort_t* attn    = (ushort_t*)d_ws;                    // 8,847,360 ushorts
    ushort_t* Xt      = attn + 8847360;                     // 2,097,152
    ushort_t* Wt      = Xt + 2097152;                       // 196,608
    float*    rowAgg  = (float*)(Wt + 196608);              // 61,440
    float*    meanArr = rowAgg + 61440;                     // 4800
    float*    rstdArr = meanArr + 4800;                     // 4800

    prep<<<2816, 256, 0, stream>>>(x, conv_w, Xt, Wt);
    conv_gemm<<<dim3(128, 12), 256, 0, stream>>>(Wt, Xt, conv_b, attn, rowAgg);
    gnfin<<<192, 64, 0, stream>>>(rowAgg, meanArr, rstdArr);
    local_attn<<<512, 128, 0, stream>>>(attn, meanArr, rstdArr, gn_w, gn_b, out);
}

// Round 7
// 143.745 us; speedup vs baseline: 1.2255x; 1.2255x over previous
//
#include <hip/hip_runtime.h>
#include <hip/hip_bf16.h>

#define B_    8
#define CIN   256
#define COUT  768
#define G_    24
#define PW    40         // padded row width (16B-aligned rows)
#define PLANE 1440       // 40*36
#define EPS_  1e-5f

typedef float f32x4 __attribute__((ext_vector_type(4)));
typedef short s16x8 __attribute__((ext_vector_type(8)));
typedef unsigned short ushort_t;
typedef unsigned short u16x4 __attribute__((ext_vector_type(4)));
typedef unsigned long long ull_t;

static __device__ __forceinline__ ushort_t f2bf(float f) {
    union { float f; unsigned u; } a; a.f = f;
    const unsigned u = a.u;
    const unsigned r = u + 0x7FFFu + ((u >> 16) & 1u);
    return (ushort_t)(r >> 16);
}
static __device__ __forceinline__ float bf2f(ushort_t h) {
    union { unsigned u; float f; } a; a.u = ((unsigned)h) << 16; return a.f;
}

// ---------------- Kernel 0: prep (Xt transpose+cvt, Wt cvt) ----------------
__launch_bounds__(256)
__global__ void prep(const float* __restrict__ x, const float* __restrict__ w,
                     ushort_t* __restrict__ Xt, ushort_t* __restrict__ Wt) {
    const int z = blockIdx.x;
    const int t = threadIdx.x;
    if (z < 2048) {
        __shared__ ushort_t tile[32][33];
        const int b  = z >> 8, rem = z & 255;
        const int k0 = (rem >> 5) * 32, n0 = (rem & 31) * 32;
        const int kk = t >> 5, nn = t & 31;
        #pragma unroll
        for (int it = 0; it < 4; ++it) {
            const int kr = kk + it * 8;
            tile[kr][nn] = f2bf(x[((size_t)(b * 256 + k0 + kr)) * 1024 + n0 + nn]);
        }
        __syncthreads();
        const int kk2 = t & 31, nb = t >> 5;
        #pragma unroll
        for (int it = 0; it < 4; ++it) {
            const int nr = nb + it * 8;
            Xt[((size_t)(b * 1024 + n0 + nr)) * 256 + k0 + kk2] = tile[kk2][nr];
        }
    } else {
        const int idx = (z - 2048) * 256 + t;   // 768*256
        Wt[idx] = f2bf(w[idx]);
    }
}

// ---------------- Kernel 1: bf16 MFMA GEMM -> padded bf16 attn + rowAgg ------
__launch_bounds__(256)
__global__ void conv_gemm(const ushort_t* __restrict__ Wt, const ushort_t* __restrict__ Xt,
                          const float* __restrict__ bias, ushort_t* __restrict__ attn,
                          float* __restrict__ rowAgg) {
    const int t = threadIdx.x;
    const int wv = t >> 6, lane = t & 63;
    const int q = lane >> 4, l15 = lane & 15;
    const int m0 = blockIdx.y * 64;
    const int mw = wv * 16;
    const int n_t = blockIdx.x * 64;
    const int b = n_t >> 10, nl0 = n_t & 1023;
    const int y0 = nl0 >> 5;

    __shared__ ushort_t Ct[64][2][44];
    __shared__ float red[128][11];

    const ushort_t* aP = Wt + (size_t)(m0 + mw + l15) * 256 + q * 8;
    const ushort_t* bP = Xt + (size_t)(b * 1024 + nl0 + l15) * 256 + q * 8;

    f32x4 acc[4] = {{0,0,0,0},{0,0,0,0},{0,0,0,0},{0,0,0,0}};
    #pragma unroll
    for (int k0 = 0; k0 < 256; k0 += 32) {
        const s16x8 a  = *(const s16x8*)(aP + k0);
        const s16x8 b0 = *(const s16x8*)(bP + k0);
        const s16x8 b1 = *(const s16x8*)(bP + 16 * 256 + k0);
        const s16x8 b2 = *(const s16x8*)(bP + 32 * 256 + k0);
        const s16x8 b3 = *(const s16x8*)(bP + 48 * 256 + k0);
        acc[0] = __builtin_amdgcn_mfma_f32_16x16x32_bf16(a, b0, acc[0], 0, 0, 0);
        acc[1] = __builtin_amdgcn_mfma_f32_16x16x32_bf16(a, b1, acc[1], 0, 0, 0);
        acc[2] = __builtin_amdgcn_mfma_f32_16x16x32_bf16(a, b2, acc[2], 0, 0, 0);
        acc[3] = __builtin_amdgcn_mfma_f32_16x16x32_bf16(a, b3, acc[3], 0, 0, 0);
    }

    float bb[4];
    #pragma unroll
    for (int r = 0; r < 4; ++r) bb[r] = bias[m0 + mw + q * 4 + r];
    #pragma unroll
    for (int j = 0; j < 4; ++j) {
        const int yy = j >> 1, xx = (j & 1) * 16 + l15;
        #pragma unroll
        for (int r = 0; r < 4; ++r)
            Ct[mw + q * 4 + r][yy][2 + xx] = f2bf(acc[j][r] + bb[r]);
    }
    #pragma unroll
    for (int it = 0; it < 2; ++it) {
        const int id = it * 256 + t;
        const int m = id >> 3, yy = (id >> 2) & 1, pos = id & 3;
        const int us = (pos == 0) ? 0 : (32 + 2 * pos);
        *(unsigned*)&Ct[m][yy][us] = 0u;
    }
    __syncthreads();

    ushort_t* pb = attn + ((size_t)(b * COUT + m0)) * PLANE;
    #pragma unroll
    for (int it = 0; it < 5; ++it) {
        const int id = it * 256 + t;
        const int m = id / 20, rem = id % 20, yy = rem / 10, s = rem % 10;
        const ull_t v = *(const ull_t*)&Ct[m][yy][s * 4];
        *(ull_t*)(pb + (size_t)m * PLANE + (y0 + yy + 2) * PW + s * 4) = v;
    }
    if (y0 == 0 || y0 == 30) {
        const int rowA = (y0 == 0) ? 0 : 34;
        #pragma unroll
        for (int it = 0; it < 5; ++it) {
            const int id = it * 256 + t;
            const int m = id / 20, rem = id % 20, yy = rem / 10, s = rem % 10;
            *(ull_t*)(pb + (size_t)m * PLANE + (rowA + yy) * PW + s * 4) = 0ull;
        }
    }

    if (t < 128) {
        const int gi = t >> 6, yy = (t >> 5) & 1, c = t & 31;
        const int m = gi * 32 + c;
        float lin = 0.f, sq = 0.f, e0 = 0.f, e1 = 0.f, e30 = 0.f, e31 = 0.f;
        #pragma unroll
        for (int u = 0; u < 9; ++u) {
            const ull_t vv = *(const ull_t*)&Ct[m][yy][u * 4];
            const unsigned lo = (unsigned)vv, hi = (unsigned)(vv >> 32);
            union { unsigned u; float f; } f0, f1, f2, f3;
            f0.u = lo << 16; f1.u = lo & 0xffff0000u;
            f2.u = hi << 16; f3.u = hi & 0xffff0000u;
            lin += (f0.f + f1.f) + (f2.f + f3.f);
            sq  += (f0.f * f0.f + f1.f * f1.f) + (f2.f * f2.f + f3.f * f3.f);
            if (u == 0) { e0 = f2.f; e1 = f3.f; }
            if (u == 8) { e30 = f0.f; e31 = f1.f; }
        }
        red[t][0] = lin; red[t][1] = sq;
        red[t][2] = e0;  red[t][3] = e0 * e0;
        red[t][4] = e1;  red[t][5] = e1 * e1;
        red[t][6] = e30; red[t][7] = e30 * e30;
        red[t][8] = e31; red[t][9] = e31 * e31;
    }
    __syncthreads();
    if (t < 40) {
        const int s = t % 10, gy = t / 10;
        const int gi = gy >> 1, yy = gy & 1;
        float sum = 0.f;
        #pragma unroll
        for (int c = 0; c < 32; ++c) sum += red[gi * 64 + yy * 32 + c][s];
        const int g = blockIdx.y * 2 + gi;
        rowAgg[(((size_t)b * G_ + g) * 32 + (y0 + yy)) * 10 + s] = sum;
    }
}

// ---------------- Kernel 2: tiny stats finalize ----------------
__launch_bounds__(64)
__global__ void gnfin(const float* __restrict__ rowAgg,
                      float* __restrict__ meanArr, float* __restrict__ rstdArr) {
    const int bg = blockIdx.x;
    const int t = threadIdx.x;
    __shared__ float rp[32][5], rp2[32][5];
    if (t < 32) {
        const float* a = rowAgg + ((size_t)bg * 32 + t) * 10;
        const float S = a[0], Sq = a[1];
        const float e0 = a[2], q0 = a[3], e1 = a[4], q1 = a[5];
        const float e30 = a[6], q30 = a[7], e31 = a[8], q31 = a[9];
        rp[t][0] = S - e30 - e31; rp[t][1] = S - e31; rp[t][2] = S;
        rp[t][3] = S - e0;        rp[t][4] = S - e0 - e1;
        rp2[t][0] = Sq - q30 - q31; rp2[t][1] = Sq - q31; rp2[t][2] = Sq;
        rp2[t][3] = Sq - q0;        rp2[t][4] = Sq - q0 - q1;
    }
    __syncthreads();
    if (t < 25) {
        const int kw = t % 5, kh = t / 5;
        float cs = 0.f, cs2 = 0.f;
        #pragma unroll
        for (int yy = 0; yy < 32; ++yy) { cs += rp[yy][kw]; cs2 += rp2[yy][kw]; }
        if (kh == 0)      { cs -= rp[30][kw] + rp[31][kw]; cs2 -= rp2[30][kw] + rp2[31][kw]; }
        else if (kh == 1) { cs -= rp[31][kw];              cs2 -= rp2[31][kw]; }
        else if (kh == 3) { cs -= rp[0][kw];               cs2 -= rp2[0][kw]; }
        else if (kh == 4) { cs -= rp[0][kw] + rp[1][kw];   cs2 -= rp2[0][kw] + rp2[1][kw]; }
        const float inv_n = 1.f / 32768.f;
        const float mean = cs * inv_n;
        const float var  = cs2 * inv_n - mean * mean;
        meanArr[bg * 25 + t] = mean;
        rstdArr[bg * 25 + t] = rsqrtf(var + EPS_);
    }
}

// ---------------- Kernel 3: local attention — single-wave workgroups ---------
// Block = 64 threads = 1 wave = one (b, head, 2-row slab). __syncthreads() on a
// 1-wave group is a free fence (backend elides s_barrier). Stage one channel
// plane region (6 padded rows x 40) per step with depth-2 global prefetch.
__launch_bounds__(64)
__global__ void local_attn(const ushort_t* __restrict__ attn,
                           const float* __restrict__ meanArr, const float* __restrict__ rstdArr,
                           const float* __restrict__ gn_w, const float* __restrict__ gn_b,
                           float* __restrict__ out) {
    const int blk = blockIdx.x;          // 1024 = 8b x 8n x 16 slabs
    const int b = blk >> 7;
    const int n = (blk >> 4) & 7;
    const int slab = blk & 15;
    const int i0 = slab * 2;
    const int t = threadIdx.x;           // 64
    const int r = t >> 5, j = t & 31;
    const int row = i0 + r;

    __shared__ float KB[240];
    __shared__ float QB[240];
    __shared__ float s_rq[25], s_mq[25], s_rk[25], s_ck[25], s_rv[25], s_cv[25];
    __shared__ float s_gw[96], s_gb[96];

    if (t < 25) {
        const int gk = (b * G_ + n * 3) * 25 + t;
        const float mK = meanArr[gk],      rK = rstdArr[gk];
        const float mQ = meanArr[gk + 25], rQ = rstdArr[gk + 25];
        const float mV = meanArr[gk + 50], rV = rstdArr[gk + 50];
        s_rk[t] = rK; s_ck[t] = mK * rK;
        s_rq[t] = rQ; s_mq[t] = mQ * rQ;
        s_rv[t] = rV; s_cv[t] = mV * rV;
    }
    s_gw[t] = gn_w[n * 96 + t];
    s_gb[t] = gn_b[n * 96 + t];
    if (t < 32) {
        s_gw[64 + t] = gn_w[n * 96 + 64 + t];
        s_gb[64 + t] = gn_b[n * 96 + 64 + t];
    }
    __syncthreads();

    float rq[25]; float cQ = 0.f;
    #pragma unroll
    for (int p = 0; p < 25; ++p) { rq[p] = s_rq[p]; cQ += s_mq[p]; }

    // region: padded rows i0..i0+5 (240 bf16 elems/plane); 60 stagers x u16x4
    const ushort_t* regB = attn + (size_t)(b * COUT + n * 96) * PLANE + i0 * PW;
    const bool stg = (t < 60);
    const int eo = t * 4;
    const int base = r * PW + j;

    const ushort_t* baseK = regB;
    const ushort_t* baseQ = regB + (size_t)32 * PLANE;
    const ushort_t* baseV = regB + (size_t)64 * PLANE;

    u16x4 pK0 = {0,0,0,0}, pK1 = {0,0,0,0}, pQ0 = {0,0,0,0}, pQ1 = {0,0,0,0};
    if (stg) {
        pK0 = *(const u16x4*)(baseK + eo);
        pQ0 = *(const u16x4*)(baseQ + eo);
        pK1 = *(const u16x4*)(baseK + PLANE + eo);
        pQ1 = *(const u16x4*)(baseQ + PLANE + eo);
    }

    float sal[25];
    #pragma unroll
    for (int p = 0; p < 25; ++p) sal[p] = 0.f;
    float sumQ2 = 0.f, sumQB = 0.f;

    #pragma unroll 2
    for (int ch = 0; ch < 32; ++ch) {
        if (stg) {
            f32x4 k4 = { bf2f(pK0[0]), bf2f(pK0[1]), bf2f(pK0[2]), bf2f(pK0[3]) };
            f32x4 q4 = { bf2f(pQ0[0]), bf2f(pQ0[1]), bf2f(pQ0[2]), bf2f(pQ0[3]) };
            *(f32x4*)&KB[eo] = k4;
            *(f32x4*)&QB[eo] = q4;
            pK0 = pK1; pQ0 = pQ1;
            if (ch < 30) {
                pK1 = *(const u16x4*)(baseK + (size_t)(ch + 2) * PLANE + eo);
                pQ1 = *(const u16x4*)(baseQ + (size_t)(ch + 2) * PLANE + eo);
            }
        }
        __syncthreads();   // free fence (1-wave block): staging visible to reads
        const float* qb = &QB[base];
        const float* kb = &KB[base];
        float qa0 = 0.f, qa1 = 0.f, qa2 = 0.f, qa3 = 0.f, qa4 = 0.f;
        #pragma unroll
        for (int kw = 0; kw < 5; ++kw) {
            qa0 += rq[0 * 5 + kw] * qb[0 * PW + kw];
            qa1 += rq[1 * 5 + kw] * qb[1 * PW + kw];
            qa2 += rq[2 * 5 + kw] * qb[2 * PW + kw];
            qa3 += rq[3 * 5 + kw] * qb[3 * PW + kw];
            qa4 += rq[4 * 5 + kw] * qb[4 * PW + kw];
        }
        const float qa = (qa0 + qa1) + (qa2 + qa3) + qa4;
        const float qk  = s_gw[32 + ch] * ((qa - cQ) * 0.04f) + s_gb[32 + ch];
        const float qk2 = qk * s_gw[ch];
        sumQ2 += qk2; sumQB += qk * s_gb[ch];
        #pragma unroll
        for (int kh = 0; kh < 5; ++kh)
            #pragma unroll
            for (int kw = 0; kw < 5; ++kw)
                sal[kh * 5 + kw] += qk2 * kb[kh * PW + kw];
        __syncthreads();   // free fence: reads done before next staging write
    }

    // prefetch first two V planes (hide under softmax)
    u16x4 pV0 = {0,0,0,0}, pV1 = {0,0,0,0};
    if (stg) {
        pV0 = *(const u16x4*)(baseV + eo);
        pV1 = *(const u16x4*)(baseV + PLANE + eo);
    }

    #pragma unroll
    for (int p = 0; p < 25; ++p) sal[p] = s_rk[p] * sal[p] - s_ck[p] * sumQ2 + sumQB;

    const float scale = 0.17677669529663687f;  // 1/sqrt(32)
    float mmax = -3.4e38f;
    #pragma unroll
    for (int p = 0; p < 25; ++p) { sal[p] *= scale; mmax = fmaxf(mmax, sal[p]); }
    float ssum = 0.f;
    #pragma unroll
    for (int p = 0; p < 25; ++p) { sal[p] = __expf(sal[p] - mmax); ssum += sal[p]; }
    const float rs = 1.f / ssum;
    float cV2 = 0.f;
    #pragma unroll
    for (int p = 0; p < 25; ++p) {
        const float m = sal[p] * rs;
        sal[p] = m * s_rv[p];        // reuse sal as V-tap weights
        cV2 += m * s_cv[p];
    }

    #pragma unroll 2
    for (int v = 0; v < 32; ++v) {
        if (stg) {
            f32x4 v4 = { bf2f(pV0[0]), bf2f(pV0[1]), bf2f(pV0[2]), bf2f(pV0[3]) };
            *(f32x4*)&KB[eo] = v4;
            pV0 = pV1;
            if (v < 30) pV1 = *(const u16x4*)(baseV + (size_t)(v + 2) * PLANE + eo);
        }
        __syncthreads();
        const float* vb = &KB[base];
        float a0 = 0.f, a1 = 0.f, a2 = 0.f, a3 = 0.f, a4 = 0.f;
        #pragma unroll
        for (int kw = 0; kw < 5; ++kw) {
            a0 += sal[0 * 5 + kw] * vb[0 * PW + kw];
            a1 += sal[1 * 5 + kw] * vb[1 * PW + kw];
            a2 += sal[2 * 5 + kw] * vb[2 * PW + kw];
            a3 += sal[3 * 5 + kw] * vb[3 * PW + kw];
            a4 += sal[4 * 5 + kw] * vb[4 * PW + kw];
        }
        const float acc = (a0 + a1) + (a2 + a3) + a4;
        out[((size_t)(b * 256 + n * 32 + v) * 32 + row) * 32 + j] =
            s_gw[64 + v] * acc + (s_gb[64 + v] - s_gw[64 + v] * cV2);
        __syncthreads();
    }
}

extern "C" void kernel_launch(void* const* d_in, const int* in_sizes, int n_in,
                              void* d_out, int out_size, void* d_ws, size_t ws_size,
                              hipStream_t stream) {
    const float* x      = (const float*)d_in[0];
    const float* conv_w = (const float*)d_in[1];
    const float* conv_b = (const float*)d_in[2];
    const float* gn_w   = (const float*)d_in[3];
    const float* gn_b   = (const float*)d_in[4];
    float* out = (float*)d_out;

    ushort_t* attn    = (ushort_t*)d_ws;                    // 8,847,360 ushorts
    ushort_t* Xt      = attn + 8847360;                     // 2,097,152
    ushort_t* Wt      = Xt + 2097152;                       // 196,608
    float*    rowAgg  = (float*)(Wt + 196608);              // 61,440
    float*    meanArr = rowAgg + 61440;                     // 4800
    float*    rstdArr = meanArr + 4800;                     // 4800

    prep<<<2816, 256, 0, stream>>>(x, conv_w, Xt, Wt);
    conv_gemm<<<dim3(128, 12), 256, 0, stream>>>(Wt, Xt, conv_b, attn, rowAgg);
    gnfin<<<192, 64, 0, stream>>>(rowAgg, meanArr, rstdArr);
    local_attn<<<1024, 64, 0, stream>>>(attn, meanArr, rstdArr, gn_w, gn_b, out);
}

// Round 8
// 142.024 us; speedup vs baseline: 1.2404x; 1.0121x over previous
//
#include <hip/hip_runtime.h>
#include <hip/hip_bf16.h>

#define B_    8
#define CIN   256
#define COUT  768
#define G_    24
#define PW    40         // padded row width (16B-aligned rows)
#define PLANE 1440       // 40*36
#define EPS_  1e-5f

typedef float f32x4 __attribute__((ext_vector_type(4)));
typedef short s16x8 __attribute__((ext_vector_type(8)));
typedef unsigned short ushort_t;
typedef unsigned short u16x4 __attribute__((ext_vector_type(4)));
typedef unsigned long long ull_t;

// LDS-only fence: compiler reordering barrier + s_waitcnt lgkmcnt(0).
// Does NOT wait vmcnt -> global prefetch loads stay in flight.
#define LDS_FENCE() do { asm volatile("" ::: "memory"); \
                         __builtin_amdgcn_s_waitcnt(0xC07F); \
                         asm volatile("" ::: "memory"); } while (0)

static __device__ __forceinline__ ushort_t f2bf(float f) {
    union { float f; unsigned u; } a; a.f = f;
    const unsigned u = a.u;
    const unsigned r = u + 0x7FFFu + ((u >> 16) & 1u);
    return (ushort_t)(r >> 16);
}
static __device__ __forceinline__ float bf2f(ushort_t h) {
    union { unsigned u; float f; } a; a.u = ((unsigned)h) << 16; return a.f;
}

// ---------------- Kernel 0: prep (Xt transpose+cvt, Wt cvt) ----------------
__launch_bounds__(256)
__global__ void prep(const float* __restrict__ x, const float* __restrict__ w,
                     ushort_t* __restrict__ Xt, ushort_t* __restrict__ Wt) {
    const int z = blockIdx.x;
    const int t = threadIdx.x;
    if (z < 2048) {
        __shared__ ushort_t tile[32][33];
        const int b  = z >> 8, rem = z & 255;
        const int k0 = (rem >> 5) * 32, n0 = (rem & 31) * 32;
        const int kk = t >> 5, nn = t & 31;
        #pragma unroll
        for (int it = 0; it < 4; ++it) {
            const int kr = kk + it * 8;
            tile[kr][nn] = f2bf(x[((size_t)(b * 256 + k0 + kr)) * 1024 + n0 + nn]);
        }
        __syncthreads();
        const int kk2 = t & 31, nb = t >> 5;
        #pragma unroll
        for (int it = 0; it < 4; ++it) {
            const int nr = nb + it * 8;
            Xt[((size_t)(b * 1024 + n0 + nr)) * 256 + k0 + kk2] = tile[kk2][nr];
        }
    } else {
        const int idx = (z - 2048) * 256 + t;   // 768*256
        Wt[idx] = f2bf(w[idx]);
    }
}

// ---------------- Kernel 1: bf16 MFMA GEMM -> padded bf16 attn + rowAgg ------
__launch_bounds__(256)
__global__ void conv_gemm(const ushort_t* __restrict__ Wt, const ushort_t* __restrict__ Xt,
                          const float* __restrict__ bias, ushort_t* __restrict__ attn,
                          float* __restrict__ rowAgg) {
    const int t = threadIdx.x;
    const int wv = t >> 6, lane = t & 63;
    const int q = lane >> 4, l15 = lane & 15;
    const int m0 = blockIdx.y * 64;
    const int mw = wv * 16;
    const int n_t = blockIdx.x * 64;
    const int b = n_t >> 10, nl0 = n_t & 1023;
    const int y0 = nl0 >> 5;

    __shared__ ushort_t Ct[64][2][44];
    __shared__ float red[128][11];

    const ushort_t* aP = Wt + (size_t)(m0 + mw + l15) * 256 + q * 8;
    const ushort_t* bP = Xt + (size_t)(b * 1024 + nl0 + l15) * 256 + q * 8;

    f32x4 acc[4] = {{0,0,0,0},{0,0,0,0},{0,0,0,0},{0,0,0,0}};
    #pragma unroll
    for (int k0 = 0; k0 < 256; k0 += 32) {
        const s16x8 a  = *(const s16x8*)(aP + k0);
        const s16x8 b0 = *(const s16x8*)(bP + k0);
        const s16x8 b1 = *(const s16x8*)(bP + 16 * 256 + k0);
        const s16x8 b2 = *(const s16x8*)(bP + 32 * 256 + k0);
        const s16x8 b3 = *(const s16x8*)(bP + 48 * 256 + k0);
        acc[0] = __builtin_amdgcn_mfma_f32_16x16x32_bf16(a, b0, acc[0], 0, 0, 0);
        acc[1] = __builtin_amdgcn_mfma_f32_16x16x32_bf16(a, b1, acc[1], 0, 0, 0);
        acc[2] = __builtin_amdgcn_mfma_f32_16x16x32_bf16(a, b2, acc[2], 0, 0, 0);
        acc[3] = __builtin_amdgcn_mfma_f32_16x16x32_bf16(a, b3, acc[3], 0, 0, 0);
    }

    float bb[4];
    #pragma unroll
    for (int r = 0; r < 4; ++r) bb[r] = bias[m0 + mw + q * 4 + r];
    #pragma unroll
    for (int j = 0; j < 4; ++j) {
        const int yy = j >> 1, xx = (j & 1) * 16 + l15;
        #pragma unroll
        for (int r = 0; r < 4; ++r)
            Ct[mw + q * 4 + r][yy][2 + xx] = f2bf(acc[j][r] + bb[r]);
    }
    #pragma unroll
    for (int it = 0; it < 2; ++it) {
        const int id = it * 256 + t;
        const int m = id >> 3, yy = (id >> 2) & 1, pos = id & 3;
        const int us = (pos == 0) ? 0 : (32 + 2 * pos);
        *(unsigned*)&Ct[m][yy][us] = 0u;
    }
    __syncthreads();

    ushort_t* pb = attn + ((size_t)(b * COUT + m0)) * PLANE;
    #pragma unroll
    for (int it = 0; it < 5; ++it) {
        const int id = it * 256 + t;
        const int m = id / 20, rem = id % 20, yy = rem / 10, s = rem % 10;
        const ull_t v = *(const ull_t*)&Ct[m][yy][s * 4];
        *(ull_t*)(pb + (size_t)m * PLANE + (y0 + yy + 2) * PW + s * 4) = v;
    }
    if (y0 == 0 || y0 == 30) {
        const int rowA = (y0 == 0) ? 0 : 34;
        #pragma unroll
        for (int it = 0; it < 5; ++it) {
            const int id = it * 256 + t;
            const int m = id / 20, rem = id % 20, yy = rem / 10, s = rem % 10;
            *(ull_t*)(pb + (size_t)m * PLANE + (rowA + yy) * PW + s * 4) = 0ull;
        }
    }

    if (t < 128) {
        const int gi = t >> 6, yy = (t >> 5) & 1, c = t & 31;
        const int m = gi * 32 + c;
        float lin = 0.f, sq = 0.f, e0 = 0.f, e1 = 0.f, e30 = 0.f, e31 = 0.f;
        #pragma unroll
        for (int u = 0; u < 9; ++u) {
            const ull_t vv = *(const ull_t*)&Ct[m][yy][u * 4];
            const unsigned lo = (unsigned)vv, hi = (unsigned)(vv >> 32);
            union { unsigned u; float f; } f0, f1, f2, f3;
            f0.u = lo << 16; f1.u = lo & 0xffff0000u;
            f2.u = hi << 16; f3.u = hi & 0xffff0000u;
            lin += (f0.f + f1.f) + (f2.f + f3.f);
            sq  += (f0.f * f0.f + f1.f * f1.f) + (f2.f * f2.f + f3.f * f3.f);
            if (u == 0) { e0 = f2.f; e1 = f3.f; }
            if (u == 8) { e30 = f0.f; e31 = f1.f; }
        }
        red[t][0] = lin; red[t][1] = sq;
        red[t][2] = e0;  red[t][3] = e0 * e0;
        red[t][4] = e1;  red[t][5] = e1 * e1;
        red[t][6] = e30; red[t][7] = e30 * e30;
        red[t][8] = e31; red[t][9] = e31 * e31;
    }
    __syncthreads();
    if (t < 40) {
        const int s = t % 10, gy = t / 10;
        const int gi = gy >> 1, yy = gy & 1;
        float sum = 0.f;
        #pragma unroll
        for (int c = 0; c < 32; ++c) sum += red[gi * 64 + yy * 32 + c][s];
        const int g = blockIdx.y * 2 + gi;
        rowAgg[(((size_t)b * G_ + g) * 32 + (y0 + yy)) * 10 + s] = sum;
    }
}

// ---------------- Kernel 2: tiny stats finalize ----------------
__launch_bounds__(64)
__global__ void gnfin(const float* __restrict__ rowAgg,
                      float* __restrict__ meanArr, float* __restrict__ rstdArr) {
    const int bg = blockIdx.x;
    const int t = threadIdx.x;
    __shared__ float rp[32][5], rp2[32][5];
    if (t < 32) {
        const float* a = rowAgg + ((size_t)bg * 32 + t) * 10;
        const float S = a[0], Sq = a[1];
        const float e0 = a[2], q0 = a[3], e1 = a[4], q1 = a[5];
        const float e30 = a[6], q30 = a[7], e31 = a[8], q31 = a[9];
        rp[t][0] = S - e30 - e31; rp[t][1] = S - e31; rp[t][2] = S;
        rp[t][3] = S - e0;        rp[t][4] = S - e0 - e1;
        rp2[t][0] = Sq - q30 - q31; rp2[t][1] = Sq - q31; rp2[t][2] = Sq;
        rp2[t][3] = Sq - q0;        rp2[t][4] = Sq - q0 - q1;
    }
    __syncthreads();
    if (t < 25) {
        const int kw = t % 5, kh = t / 5;
        float cs = 0.f, cs2 = 0.f;
        #pragma unroll
        for (int yy = 0; yy < 32; ++yy) { cs += rp[yy][kw]; cs2 += rp2[yy][kw]; }
        if (kh == 0)      { cs -= rp[30][kw] + rp[31][kw]; cs2 -= rp2[30][kw] + rp2[31][kw]; }
        else if (kh == 1) { cs -= rp[31][kw];              cs2 -= rp2[31][kw]; }
        else if (kh == 3) { cs -= rp[0][kw];               cs2 -= rp2[0][kw]; }
        else if (kh == 4) { cs -= rp[0][kw] + rp[1][kw];   cs2 -= rp2[0][kw] + rp2[1][kw]; }
        const float inv_n = 1.f / 32768.f;
        const float mean = cs * inv_n;
        const float var  = cs2 * inv_n - mean * mean;
        meanArr[bg * 25 + t] = mean;
        rstdArr[bg * 25 + t] = rsqrtf(var + EPS_);
    }
}

// ---------------- Kernel 3: local attention — 1-wave blocks, double-buffered,
// fence-only pipeline (no barriers in loops) ----------------
__launch_bounds__(64)
__global__ void local_attn(const ushort_t* __restrict__ attn,
                           const float* __restrict__ meanArr, const float* __restrict__ rstdArr,
                           const float* __restrict__ gn_w, const float* __restrict__ gn_b,
                           float* __restrict__ out) {
    const int blk = blockIdx.x;          // 1024 = 8b x 8n x 16 slabs
    const int b = blk >> 7;
    const int n = (blk >> 4) & 7;
    const int slab = blk & 15;
    const int i0 = slab * 2;
    const int t = threadIdx.x;           // 64
    const int r = t >> 5, j = t & 31;
    const int row = i0 + r;

    __shared__ float KB[2][240];
    __shared__ float QB[2][240];
    __shared__ float s_rq[25], s_mq[25], s_rk[25], s_ck[25], s_rv[25], s_cv[25];
    __shared__ float s_gw[96], s_gb[96];

    if (t < 25) {
        const int gk = (b * G_ + n * 3) * 25 + t;
        const float mK = meanArr[gk],      rK = rstdArr[gk];
        const float mQ = meanArr[gk + 25], rQ = rstdArr[gk + 25];
        const float mV = meanArr[gk + 50], rV = rstdArr[gk + 50];
        s_rk[t] = rK; s_ck[t] = mK * rK;
        s_rq[t] = rQ; s_mq[t] = mQ * rQ;
        s_rv[t] = rV; s_cv[t] = mV * rV;
    }
    s_gw[t] = gn_w[n * 96 + t];
    s_gb[t] = gn_b[n * 96 + t];
    if (t < 32) {
        s_gw[64 + t] = gn_w[n * 96 + 64 + t];
        s_gb[64 + t] = gn_b[n * 96 + 64 + t];
    }
    __syncthreads();

    float rq[25]; float cQ = 0.f;
    #pragma unroll
    for (int p = 0; p < 25; ++p) { rq[p] = s_rq[p]; cQ += s_mq[p]; }

    // region: padded rows i0..i0+5 (240 bf16 elems/plane); 60 stagers x u16x4
    const ushort_t* regB = attn + (size_t)(b * COUT + n * 96) * PLANE + i0 * PW;
    const bool stg = (t < 60);
    const int eo = t * 4;
    const int base = r * PW + j;

    const ushort_t* baseK = regB;
    const ushort_t* baseQ = regB + (size_t)32 * PLANE;
    const ushort_t* baseV = regB + (size_t)64 * PLANE;

    // rolling regs: nX = plane to store next (ch+1), fX = fetch in flight (ch+2)
    u16x4 nK = {0,0,0,0}, nQ = {0,0,0,0}, fK = {0,0,0,0}, fQ = {0,0,0,0};
    if (stg) {
        const u16x4 c0K = *(const u16x4*)(baseK + eo);
        const u16x4 c0Q = *(const u16x4*)(baseQ + eo);
        nK = *(const u16x4*)(baseK + PLANE + eo);
        nQ = *(const u16x4*)(baseQ + PLANE + eo);
        fK = *(const u16x4*)(baseK + 2 * (size_t)PLANE + eo);
        fQ = *(const u16x4*)(baseQ + 2 * (size_t)PLANE + eo);
        *(f32x4*)&KB[0][eo] = f32x4{ bf2f(c0K[0]), bf2f(c0K[1]), bf2f(c0K[2]), bf2f(c0K[3]) };
        *(f32x4*)&QB[0][eo] = f32x4{ bf2f(c0Q[0]), bf2f(c0Q[1]), bf2f(c0Q[2]), bf2f(c0Q[3]) };
    }
    LDS_FENCE();

    float sal[25];
    #pragma unroll
    for (int p = 0; p < 25; ++p) sal[p] = 0.f;
    float sumQ2 = 0.f, sumQB = 0.f;

    for (int ch = 0; ch < 32; ++ch) {
        const int buf = ch & 1;
        if (stg && ch < 31) {
            // store plane ch+1 into the other buffer while we compute from buf
            *(f32x4*)&KB[buf ^ 1][eo] = f32x4{ bf2f(nK[0]), bf2f(nK[1]), bf2f(nK[2]), bf2f(nK[3]) };
            *(f32x4*)&QB[buf ^ 1][eo] = f32x4{ bf2f(nQ[0]), bf2f(nQ[1]), bf2f(nQ[2]), bf2f(nQ[3]) };
            nK = fK; nQ = fQ;
            if (ch < 30) {
                if (ch < 29) {
                    fK = *(const u16x4*)(baseK + (size_t)(ch + 3) * PLANE + eo);
                    fQ = *(const u16x4*)(baseQ + (size_t)(ch + 3) * PLANE + eo);
                } else {       // tail: prefetch V planes 0 and 1
                    fK = *(const u16x4*)(baseV + eo);
                    fQ = *(const u16x4*)(baseV + (size_t)PLANE + eo);
                }
            }
        }
        const float* qb = &QB[buf][base];
        const float* kb = &KB[buf][base];
        float qa0 = 0.f, qa1 = 0.f, qa2 = 0.f, qa3 = 0.f, qa4 = 0.f;
        #pragma unroll
        for (int kw = 0; kw < 5; ++kw) {
            qa0 += rq[0 * 5 + kw] * qb[0 * PW + kw];
            qa1 += rq[1 * 5 + kw] * qb[1 * PW + kw];
            qa2 += rq[2 * 5 + kw] * qb[2 * PW + kw];
            qa3 += rq[3 * 5 + kw] * qb[3 * PW + kw];
            qa4 += rq[4 * 5 + kw] * qb[4 * PW + kw];
        }
        const float qa = (qa0 + qa1) + (qa2 + qa3) + qa4;
        const float qk  = s_gw[32 + ch] * ((qa - cQ) * 0.04f) + s_gb[32 + ch];
        const float qk2 = qk * s_gw[ch];
        sumQ2 += qk2; sumQB += qk * s_gb[ch];
        #pragma unroll
        for (int kh = 0; kh < 5; ++kh)
            #pragma unroll
            for (int kw = 0; kw < 5; ++kw)
                sal[kh * 5 + kw] += qk2 * kb[kh * PW + kw];
        LDS_FENCE();   // staging write for ch+1 visible before next iter's reads
    }
    // after loop: nK = V plane 0, nQ = V plane 1 (rotated in during tail)

    // V rolling regs: vA = plane to store next (v+1), vB = in flight (v+2)
    u16x4 vA = nQ, vB = {0,0,0,0};
    if (stg) {
        vB = *(const u16x4*)(baseV + 2 * (size_t)PLANE + eo);
        *(f32x4*)&KB[0][eo] = f32x4{ bf2f(nK[0]), bf2f(nK[1]), bf2f(nK[2]), bf2f(nK[3]) };  // V0
    }

    #pragma unroll
    for (int p = 0; p < 25; ++p) sal[p] = s_rk[p] * sal[p] - s_ck[p] * sumQ2 + sumQB;

    const float scale = 0.17677669529663687f;  // 1/sqrt(32)
    float mmax = -3.4e38f;
    #pragma unroll
    for (int p = 0; p < 25; ++p) { sal[p] *= scale; mmax = fmaxf(mmax, sal[p]); }
    float ssum = 0.f;
    #pragma unroll
    for (int p = 0; p < 25; ++p) { sal[p] = __expf(sal[p] - mmax); ssum += sal[p]; }
    const float rs = 1.f / ssum;
    float cV2 = 0.f;
    #pragma unroll
    for (int p = 0; p < 25; ++p) {
        const float m = sal[p] * rs;
        sal[p] = m * s_rv[p];        // reuse sal as V-tap weights
        cV2 += m * s_cv[p];
    }
    LDS_FENCE();   // V0 staged above is visible

    for (int v = 0; v < 32; ++v) {
        const int buf = v & 1;
        if (stg && v < 31) {
            *(f32x4*)&KB[buf ^ 1][eo] = f32x4{ bf2f(vA[0]), bf2f(vA[1]), bf2f(vA[2]), bf2f(vA[3]) };
            vA = vB;
            if (v < 29) vB = *(const u16x4*)(baseV + (size_t)(v + 3) * PLANE + eo);
        }
        const float* vb = &KB[buf][base];
        float a0 = 0.f, a1 = 0.f, a2 = 0.f, a3 = 0.f, a4 = 0.f;
        #pragma unroll
        for (int kw = 0; kw < 5; ++kw) {
            a0 += sal[0 * 5 + kw] * vb[0 * PW + kw];
            a1 += sal[1 * 5 + kw] * vb[1 * PW + kw];
            a2 += sal[2 * 5 + kw] * vb[2 * PW + kw];
            a3 += sal[3 * 5 + kw] * vb[3 * PW + kw];
            a4 += sal[4 * 5 + kw] * vb[4 * PW + kw];
        }
        const float acc = (a0 + a1) + (a2 + a3) + a4;
        out[((size_t)(b * 256 + n * 32 + v) * 32 + row) * 32 + j] =
            s_gw[64 + v] * acc + (s_gb[64 + v] - s_gw[64 + v] * cV2);
        LDS_FENCE();
    }
}

extern "C" void kernel_launch(void* const* d_in, const int* in_sizes, int n_in,
                              void* d_out, int out_size, void* d_ws, size_t ws_size,
                              hipStream_t stream) {
    const float* x      = (const float*)d_in[0];
    const float* conv_w = (const float*)d_in[1];
    const float* conv_b = (const float*)d_in[2];
    const float* gn_w   = (const float*)d_in[3];
    const float* gn_b   = (const float*)d_in[4];
    float* out = (float*)d_out;

    ushort_t* attn    = (ushort_t*)d_ws;                    // 8,847,360 ushorts
    ushort_t* Xt      = attn + 8847360;                     // 2,097,152
    ushort_t* Wt      = Xt + 2097152;                       // 196,608
    float*    rowAgg  = (float*)(Wt + 196608);              // 61,440
    float*    meanArr = rowAgg + 61440;                     // 4800
    float*    rstdArr = meanArr + 4800;                     // 4800

    prep<<<2816, 256, 0, stream>>>(x, conv_w, Xt, Wt);
    conv_gemm<<<dim3(128, 12), 256, 0, stream>>>(Wt, Xt, conv_b, attn, rowAgg);
    gnfin<<<192, 64, 0, stream>>>(rowAgg, meanArr, rstdArr);
    local_attn<<<1024, 64, 0, stream>>>(attn, meanArr, rstdArr, gn_w, gn_b, out);
}

// Round 9
// 132.611 us; speedup vs baseline: 1.3284x; 1.0710x over previous
//
#include <hip/hip_runtime.h>
#include <hip/hip_bf16.h>

#define B_    8
#define CIN   256
#define COUT  768
#define G_    24
#define PW    40         // padded row width (16B-aligned rows)
#define PLANE 1440       // 40*36
#define EPS_  1e-5f

typedef float f32x4 __attribute__((ext_vector_type(4)));
typedef short s16x8 __attribute__((ext_vector_type(8)));
typedef unsigned short ushort_t;
typedef unsigned short u16x4 __attribute__((ext_vector_type(4)));
typedef unsigned long long ull_t;

// LDS-only fence: compiler reordering barrier + s_waitcnt lgkmcnt(0).
// Does NOT wait vmcnt -> global prefetch loads stay in flight.
#define LDS_FENCE() do { asm volatile("" ::: "memory"); \
                         __builtin_amdgcn_s_waitcnt(0xC07F); \
                         asm volatile("" ::: "memory"); } while (0)

static __device__ __forceinline__ ushort_t f2bf(float f) {
    union { float f; unsigned u; } a; a.f = f;
    const unsigned u = a.u;
    const unsigned r = u + 0x7FFFu + ((u >> 16) & 1u);
    return (ushort_t)(r >> 16);
}
static __device__ __forceinline__ float bf2f(ushort_t h) {
    union { unsigned u; float f; } a; a.u = ((unsigned)h) << 16; return a.f;
}
static __device__ __forceinline__ void st4(float* dst, u16x4 v) {
    *(f32x4*)dst = f32x4{ bf2f(v[0]), bf2f(v[1]), bf2f(v[2]), bf2f(v[3]) };
}

// ---------------- Kernel 0: prep (Xt transpose+cvt, Wt cvt) ----------------
__launch_bounds__(256)
__global__ void prep(const float* __restrict__ x, const float* __restrict__ w,
                     ushort_t* __restrict__ Xt, ushort_t* __restrict__ Wt) {
    const int z = blockIdx.x;
    const int t = threadIdx.x;
    if (z < 2048) {
        __shared__ ushort_t tile[32][33];
        const int b  = z >> 8, rem = z & 255;
        const int k0 = (rem >> 5) * 32, n0 = (rem & 31) * 32;
        const int kk = t >> 5, nn = t & 31;
        #pragma unroll
        for (int it = 0; it < 4; ++it) {
            const int kr = kk + it * 8;
            tile[kr][nn] = f2bf(x[((size_t)(b * 256 + k0 + kr)) * 1024 + n0 + nn]);
        }
        __syncthreads();
        const int kk2 = t & 31, nb = t >> 5;
        #pragma unroll
        for (int it = 0; it < 4; ++it) {
            const int nr = nb + it * 8;
            Xt[((size_t)(b * 1024 + n0 + nr)) * 256 + k0 + kk2] = tile[kk2][nr];
        }
    } else {
        const int idx = (z - 2048) * 256 + t;   // 768*256
        Wt[idx] = f2bf(w[idx]);
    }
}

// ---------------- Kernel 1: bf16 MFMA GEMM -> padded bf16 attn + rowAgg ------
__launch_bounds__(256)
__global__ void conv_gemm(const ushort_t* __restrict__ Wt, const ushort_t* __restrict__ Xt,
                          const float* __restrict__ bias, ushort_t* __restrict__ attn,
                          float* __restrict__ rowAgg) {
    const int t = threadIdx.x;
    const int wv = t >> 6, lane = t & 63;
    const int q = lane >> 4, l15 = lane & 15;
    const int m0 = blockIdx.y * 64;
    const int mw = wv * 16;
    const int n_t = blockIdx.x * 64;
    const int b = n_t >> 10, nl0 = n_t & 1023;
    const int y0 = nl0 >> 5;

    __shared__ ushort_t Ct[64][2][44];
    __shared__ float red[128][11];

    const ushort_t* aP = Wt + (size_t)(m0 + mw + l15) * 256 + q * 8;
    const ushort_t* bP = Xt + (size_t)(b * 1024 + nl0 + l15) * 256 + q * 8;

    f32x4 acc[4] = {{0,0,0,0},{0,0,0,0},{0,0,0,0},{0,0,0,0}};
    #pragma unroll
    for (int k0 = 0; k0 < 256; k0 += 32) {
        const s16x8 a  = *(const s16x8*)(aP + k0);
        const s16x8 b0 = *(const s16x8*)(bP + k0);
        const s16x8 b1 = *(const s16x8*)(bP + 16 * 256 + k0);
        const s16x8 b2 = *(const s16x8*)(bP + 32 * 256 + k0);
        const s16x8 b3 = *(const s16x8*)(bP + 48 * 256 + k0);
        acc[0] = __builtin_amdgcn_mfma_f32_16x16x32_bf16(a, b0, acc[0], 0, 0, 0);
        acc[1] = __builtin_amdgcn_mfma_f32_16x16x32_bf16(a, b1, acc[1], 0, 0, 0);
        acc[2] = __builtin_amdgcn_mfma_f32_16x16x32_bf16(a, b2, acc[2], 0, 0, 0);
        acc[3] = __builtin_amdgcn_mfma_f32_16x16x32_bf16(a, b3, acc[3], 0, 0, 0);
    }

    float bb[4];
    #pragma unroll
    for (int r = 0; r < 4; ++r) bb[r] = bias[m0 + mw + q * 4 + r];
    #pragma unroll
    for (int j = 0; j < 4; ++j) {
        const int yy = j >> 1, xx = (j & 1) * 16 + l15;
        #pragma unroll
        for (int r = 0; r < 4; ++r)
            Ct[mw + q * 4 + r][yy][2 + xx] = f2bf(acc[j][r] + bb[r]);
    }
    #pragma unroll
    for (int it = 0; it < 2; ++it) {
        const int id = it * 256 + t;
        const int m = id >> 3, yy = (id >> 2) & 1, pos = id & 3;
        const int us = (pos == 0) ? 0 : (32 + 2 * pos);
        *(unsigned*)&Ct[m][yy][us] = 0u;
    }
    __syncthreads();

    ushort_t* pb = attn + ((size_t)(b * COUT + m0)) * PLANE;
    #pragma unroll
    for (int it = 0; it < 5; ++it) {
        const int id = it * 256 + t;
        const int m = id / 20, rem = id % 20, yy = rem / 10, s = rem % 10;
        const ull_t v = *(const ull_t*)&Ct[m][yy][s * 4];
        *(ull_t*)(pb + (size_t)m * PLANE + (y0 + yy + 2) * PW + s * 4) = v;
    }
    if (y0 == 0 || y0 == 30) {
        const int rowA = (y0 == 0) ? 0 : 34;
        #pragma unroll
        for (int it = 0; it < 5; ++it) {
            const int id = it * 256 + t;
            const int m = id / 20, rem = id % 20, yy = rem / 10, s = rem % 10;
            *(ull_t*)(pb + (size_t)m * PLANE + (rowA + yy) * PW + s * 4) = 0ull;
        }
    }

    if (t < 128) {
        const int gi = t >> 6, yy = (t >> 5) & 1, c = t & 31;
        const int m = gi * 32 + c;
        float lin = 0.f, sq = 0.f, e0 = 0.f, e1 = 0.f, e30 = 0.f, e31 = 0.f;
        #pragma unroll
        for (int u = 0; u < 9; ++u) {
            const ull_t vv = *(const ull_t*)&Ct[m][yy][u * 4];
            const unsigned lo = (unsigned)vv, hi = (unsigned)(vv >> 32);
            union { unsigned u; float f; } f0, f1, f2, f3;
            f0.u = lo << 16; f1.u = lo & 0xffff0000u;
            f2.u = hi << 16; f3.u = hi & 0xffff0000u;
            lin += (f0.f + f1.f) + (f2.f + f3.f);
            sq  += (f0.f * f0.f + f1.f * f1.f) + (f2.f * f2.f + f3.f * f3.f);
            if (u == 0) { e0 = f2.f; e1 = f3.f; }
            if (u == 8) { e30 = f0.f; e31 = f1.f; }
        }
        red[t][0] = lin; red[t][1] = sq;
        red[t][2] = e0;  red[t][3] = e0 * e0;
        red[t][4] = e1;  red[t][5] = e1 * e1;
        red[t][6] = e30; red[t][7] = e30 * e30;
        red[t][8] = e31; red[t][9] = e31 * e31;
    }
    __syncthreads();
    if (t < 40) {
        const int s = t % 10, gy = t / 10;
        const int gi = gy >> 1, yy = gy & 1;
        float sum = 0.f;
        #pragma unroll
        for (int c = 0; c < 32; ++c) sum += red[gi * 64 + yy * 32 + c][s];
        const int g = blockIdx.y * 2 + gi;
        rowAgg[(((size_t)b * G_ + g) * 32 + (y0 + yy)) * 10 + s] = sum;
    }
}

// ---------------- Kernel 2: tiny stats finalize ----------------
__launch_bounds__(64)
__global__ void gnfin(const float* __restrict__ rowAgg,
                      float* __restrict__ meanArr, float* __restrict__ rstdArr) {
    const int bg = blockIdx.x;
    const int t = threadIdx.x;
    __shared__ float rp[32][5], rp2[32][5];
    if (t < 32) {
        const float* a = rowAgg + ((size_t)bg * 32 + t) * 10;
        const float S = a[0], Sq = a[1];
        const float e0 = a[2], q0 = a[3], e1 = a[4], q1 = a[5];
        const float e30 = a[6], q30 = a[7], e31 = a[8], q31 = a[9];
        rp[t][0] = S - e30 - e31; rp[t][1] = S - e31; rp[t][2] = S;
        rp[t][3] = S - e0;        rp[t][4] = S - e0 - e1;
        rp2[t][0] = Sq - q30 - q31; rp2[t][1] = Sq - q31; rp2[t][2] = Sq;
        rp2[t][3] = Sq - q0;        rp2[t][4] = Sq - q0 - q1;
    }
    __syncthreads();
    if (t < 25) {
        const int kw = t % 5, kh = t / 5;
        float cs = 0.f, cs2 = 0.f;
        #pragma unroll
        for (int yy = 0; yy < 32; ++yy) { cs += rp[yy][kw]; cs2 += rp2[yy][kw]; }
        if (kh == 0)      { cs -= rp[30][kw] + rp[31][kw]; cs2 -= rp2[30][kw] + rp2[31][kw]; }
        else if (kh == 1) { cs -= rp[31][kw];              cs2 -= rp2[31][kw]; }
        else if (kh == 3) { cs -= rp[0][kw];               cs2 -= rp2[0][kw]; }
        else if (kh == 4) { cs -= rp[0][kw] + rp[1][kw];   cs2 -= rp2[0][kw] + rp2[1][kw]; }
        const float inv_n = 1.f / 32768.f;
        const float mean = cs * inv_n;
        const float var  = cs2 * inv_n - mean * mean;
        meanArr[bg * 25 + t] = mean;
        rstdArr[bg * 25 + t] = rsqrtf(var + EPS_);
    }
}

// ---------------- Kernel 3: local attention — 1-wave blocks, 1-row slabs,
// intra-wave channel split (lanes 0-31: ch 0-15, lanes 32-63: ch 16-31),
// double-buffered LDS, fence-only pipeline, shuffle combine ----------------
__launch_bounds__(64)
__global__ void local_attn(const ushort_t* __restrict__ attn,
                           const float* __restrict__ meanArr, const float* __restrict__ rstdArr,
                           const float* __restrict__ gn_w, const float* __restrict__ gn_b,
                           float* __restrict__ out) {
    const int blk = blockIdx.x;          // 2048 = b(8) x n(8) x row(32)
    const int b = blk >> 8;
    const int n = (blk >> 5) & 7;
    const int i0 = blk & 31;             // image row
    const int t = threadIdx.x;           // 64
    const int h = t >> 5;                // channel half
    const int j = t & 31;                // pixel column

    __shared__ float KB[2][2][208];      // [half][buf][5 rows x 40 + pad]
    __shared__ float QB[2][2][208];
    __shared__ float s_rq[25], s_mq[25], s_rk[25], s_ck[25], s_rv[25], s_cv[25];
    __shared__ float s_gw[96], s_gb[96];

    if (t < 25) {
        const int gk = (b * G_ + n * 3) * 25 + t;
        const float mK = meanArr[gk],      rK = rstdArr[gk];
        const float mQ = meanArr[gk + 25], rQ = rstdArr[gk + 25];
        const float mV = meanArr[gk + 50], rV = rstdArr[gk + 50];
        s_rk[t] = rK; s_ck[t] = mK * rK;
        s_rq[t] = rQ; s_mq[t] = mQ * rQ;
        s_rv[t] = rV; s_cv[t] = mV * rV;
    }
    s_gw[t] = gn_w[n * 96 + t];
    s_gb[t] = gn_b[n * 96 + t];
    if (t < 32) {
        s_gw[64 + t] = gn_w[n * 96 + 64 + t];
        s_gb[64 + t] = gn_b[n * 96 + 64 + t];
    }
    __syncthreads();

    float rq[25]; float cQ = 0.f;
    #pragma unroll
    for (int p = 0; p < 25; ++p) { rq[p] = s_rq[p]; cQ += s_mq[p]; }

    // region: padded rows i0..i0+4 (window of image row i0), 200 bf16/plane.
    // stagers: lanes with j<25 in each half, two 4-elem chunks each.
    const ushort_t* regB = attn + (size_t)(b * COUT + n * 96) * PLANE + i0 * PW;
    const bool stg = (j < 25);
    const int eo1 = j * 4, eo2 = (j + 25) * 4;

    const ushort_t* baseK = regB + (size_t)(h * 16) * PLANE;
    const ushort_t* baseQ = regB + (size_t)(32 + h * 16) * PLANE;
    const ushort_t* baseV = regB + (size_t)(64 + h * 16) * PLANE;

    u16x4 nK1{0,0,0,0}, nK2{0,0,0,0}, nQ1{0,0,0,0}, nQ2{0,0,0,0};
    u16x4 fK1{0,0,0,0}, fK2{0,0,0,0}, fQ1{0,0,0,0}, fQ2{0,0,0,0};
    if (stg) {
        const u16x4 a1 = *(const u16x4*)(baseK + eo1), a2 = *(const u16x4*)(baseK + eo2);
        const u16x4 q1 = *(const u16x4*)(baseQ + eo1), q2 = *(const u16x4*)(baseQ + eo2);
        st4(&KB[h][0][eo1], a1); st4(&KB[h][0][eo2], a2);
        st4(&QB[h][0][eo1], q1); st4(&QB[h][0][eo2], q2);
        nK1 = *(const u16x4*)(baseK + PLANE + eo1); nK2 = *(const u16x4*)(baseK + PLANE + eo2);
        nQ1 = *(const u16x4*)(baseQ + PLANE + eo1); nQ2 = *(const u16x4*)(baseQ + PLANE + eo2);
        fK1 = *(const u16x4*)(baseK + 2 * (size_t)PLANE + eo1);
        fK2 = *(const u16x4*)(baseK + 2 * (size_t)PLANE + eo2);
        fQ1 = *(const u16x4*)(baseQ + 2 * (size_t)PLANE + eo1);
        fQ2 = *(const u16x4*)(baseQ + 2 * (size_t)PLANE + eo2);
    }
    LDS_FENCE();

    float sal[25];
    #pragma unroll
    for (int p = 0; p < 25; ++p) sal[p] = 0.f;
    float sumQ2 = 0.f, sumQB = 0.f;

    for (int cc = 0; cc < 16; ++cc) {
        const int buf = cc & 1;
        if (stg && cc < 15) {
            st4(&KB[h][buf ^ 1][eo1], nK1); st4(&KB[h][buf ^ 1][eo2], nK2);
            st4(&QB[h][buf ^ 1][eo1], nQ1); st4(&QB[h][buf ^ 1][eo2], nQ2);
            nK1 = fK1; nK2 = fK2; nQ1 = fQ1; nQ2 = fQ2;
            if (cc < 13) {
                fK1 = *(const u16x4*)(baseK + (size_t)(cc + 3) * PLANE + eo1);
                fK2 = *(const u16x4*)(baseK + (size_t)(cc + 3) * PLANE + eo2);
                fQ1 = *(const u16x4*)(baseQ + (size_t)(cc + 3) * PLANE + eo1);
                fQ2 = *(const u16x4*)(baseQ + (size_t)(cc + 3) * PLANE + eo2);
            } else if (cc == 13) {   // tail: prefetch V planes 0 and 1
                fK1 = *(const u16x4*)(baseV + eo1);
                fK2 = *(const u16x4*)(baseV + eo2);
                fQ1 = *(const u16x4*)(baseV + (size_t)PLANE + eo1);
                fQ2 = *(const u16x4*)(baseV + (size_t)PLANE + eo2);
            }
        }
        const int ch = h * 16 + cc;
        const float* qb = &QB[h][buf][j];
        const float* kb = &KB[h][buf][j];
        float qa0 = 0.f, qa1 = 0.f, qa2 = 0.f, qa3 = 0.f, qa4 = 0.f;
        #pragma unroll
        for (int kw = 0; kw < 5; ++kw) {
            qa0 += rq[0 * 5 + kw] * qb[0 * PW + kw];
            qa1 += rq[1 * 5 + kw] * qb[1 * PW + kw];
            qa2 += rq[2 * 5 + kw] * qb[2 * PW + kw];
            qa3 += rq[3 * 5 + kw] * qb[3 * PW + kw];
            qa4 += rq[4 * 5 + kw] * qb[4 * PW + kw];
        }
        const float qa = (qa0 + qa1) + (qa2 + qa3) + qa4;
        const float qk  = s_gw[32 + ch] * ((qa - cQ) * 0.04f) + s_gb[32 + ch];
        const float qk2 = qk * s_gw[ch];
        sumQ2 += qk2; sumQB += qk * s_gb[ch];
        #pragma unroll
        for (int kh = 0; kh < 5; ++kh)
            #pragma unroll
            for (int kw = 0; kw < 5; ++kw)
                sal[kh * 5 + kw] += qk2 * kb[kh * PW + kw];
        LDS_FENCE();
    }
    // after loop: nK = V plane 0, nQ = V plane 1 (rotated in via tail fetch)

    u16x4 vA1 = nQ1, vA2 = nQ2, vB1{0,0,0,0}, vB2{0,0,0,0};
    if (stg) {
        st4(&KB[h][0][eo1], nK1); st4(&KB[h][0][eo2], nK2);   // V0 -> buf0
        vB1 = *(const u16x4*)(baseV + 2 * (size_t)PLANE + eo1);
        vB2 = *(const u16x4*)(baseV + 2 * (size_t)PLANE + eo2);
    }

    // combine channel halves (lanes t <-> t^32)
    sumQ2 += __shfl_xor(sumQ2, 32);
    sumQB += __shfl_xor(sumQB, 32);
    #pragma unroll
    for (int p = 0; p < 25; ++p) sal[p] += __shfl_xor(sal[p], 32);

    #pragma unroll
    for (int p = 0; p < 25; ++p) sal[p] = s_rk[p] * sal[p] - s_ck[p] * sumQ2 + sumQB;

    const float scale = 0.17677669529663687f;  // 1/sqrt(32)
    float mmax = -3.4e38f;
    #pragma unroll
    for (int p = 0; p < 25; ++p) { sal[p] *= scale; mmax = fmaxf(mmax, sal[p]); }
    float ssum = 0.f;
    #pragma unroll
    for (int p = 0; p < 25; ++p) { sal[p] = __expf(sal[p] - mmax); ssum += sal[p]; }
    const float rs = 1.f / ssum;
    float cV2 = 0.f;
    #pragma unroll
    for (int p = 0; p < 25; ++p) {
        const float m = sal[p] * rs;
        sal[p] = m * s_rv[p];        // reuse sal as V-tap weights
        cV2 += m * s_cv[p];
    }
    LDS_FENCE();   // V0 staged above is visible

    for (int cc = 0; cc < 16; ++cc) {
        const int buf = cc & 1;
        if (stg && cc < 15) {
            st4(&KB[h][buf ^ 1][eo1], vA1); st4(&KB[h][buf ^ 1][eo2], vA2);
            vA1 = vB1; vA2 = vB2;
            if (cc < 13) {
                vB1 = *(const u16x4*)(baseV + (size_t)(cc + 3) * PLANE + eo1);
                vB2 = *(const u16x4*)(baseV + (size_t)(cc + 3) * PLANE + eo2);
            }
        }
        const int v = h * 16 + cc;
        const float* vb = &KB[h][buf][j];
        float a0 = 0.f, a1 = 0.f, a2 = 0.f, a3 = 0.f, a4 = 0.f;
        #pragma unroll
        for (int kw = 0; kw < 5; ++kw) {
            a0 += sal[0 * 5 + kw] * vb[0 * PW + kw];
            a1 += sal[1 * 5 + kw] * vb[1 * PW + kw];
            a2 += sal[2 * 5 + kw] * vb[2 * PW + kw];
            a3 += sal[3 * 5 + kw] * vb[3 * PW + kw];
            a4 += sal[4 * 5 + kw] * vb[4 * PW + kw];
        }
        const float acc = (a0 + a1) + (a2 + a3) + a4;
        out[((size_t)(b * 256 + n * 32 + v) * 32 + i0) * 32 + j] =
            s_gw[64 + v] * acc + (s_gb[64 + v] - s_gw[64 + v] * cV2);
        LDS_FENCE();
    }
}

extern "C" void kernel_launch(void* const* d_in, const int* in_sizes, int n_in,
                              void* d_out, int out_size, void* d_ws, size_t ws_size,
                              hipStream_t stream) {
    const float* x      = (const float*)d_in[0];
    const float* conv_w = (const float*)d_in[1];
    const float* conv_b = (const float*)d_in[2];
    const float* gn_w   = (const float*)d_in[3];
    const float* gn_b   = (const float*)d_in[4];
    float* out = (float*)d_out;

    ushort_t* attn    = (ushort_t*)d_ws;                    // 8,847,360 ushorts
    ushort_t* Xt      = attn + 8847360;                     // 2,097,152
    ushort_t* Wt      = Xt + 2097152;                       // 196,608
    float*    rowAgg  = (float*)(Wt + 196608);              // 61,440
    float*    meanArr = rowAgg + 61440;                     // 4800
    float*    rstdArr = meanArr + 4800;                     // 4800

    prep<<<2816, 256, 0, stream>>>(x, conv_w, Xt, Wt);
    conv_gemm<<<dim3(128, 12), 256, 0, stream>>>(Wt, Xt, conv_b, attn, rowAgg);
    gnfin<<<192, 64, 0, stream>>>(rowAgg, meanArr, rstdArr);
    local_attn<<<2048, 64, 0, stream>>>(attn, meanArr, rstdArr, gn_w, gn_b, out);
}

// Round 10
// 122.344 us; speedup vs baseline: 1.4399x; 1.0839x over previous
//
#include <hip/hip_runtime.h>
#include <hip/hip_bf16.h>

#define B_    8
#define CIN   256
#define COUT  768
#define G_    24
#define PW    40         // padded row width (16B-aligned rows)
#define PLANE 1440       // 40*36
#define EPS_  1e-5f

typedef float f32x4 __attribute__((ext_vector_type(4)));
typedef short s16x8 __attribute__((ext_vector_type(8)));
typedef unsigned short ushort_t;
typedef unsigned short u16x4 __attribute__((ext_vector_type(4)));
typedef unsigned long long ull_t;

// LDS-only fence: compiler reordering barrier + s_waitcnt lgkmcnt(0).
// Does NOT wait vmcnt -> global prefetch loads stay in flight.
#define LDS_FENCE() do { asm volatile("" ::: "memory"); \
                         __builtin_amdgcn_s_waitcnt(0xC07F); \
                         asm volatile("" ::: "memory"); } while (0)

static __device__ __forceinline__ ushort_t f2bf(float f) {
    union { float f; unsigned u; } a; a.f = f;
    const unsigned u = a.u;
    const unsigned r = u + 0x7FFFu + ((u >> 16) & 1u);
    return (ushort_t)(r >> 16);
}
static __device__ __forceinline__ float bf2f(ushort_t h) {
    union { unsigned u; float f; } a; a.u = ((unsigned)h) << 16; return a.f;
}
static __device__ __forceinline__ void st4(float* dst, u16x4 v) {
    *(f32x4*)dst = f32x4{ bf2f(v[0]), bf2f(v[1]), bf2f(v[2]), bf2f(v[3]) };
}
static __device__ __forceinline__ unsigned pk2(float lo, float hi) {
    return (unsigned)f2bf(lo) | ((unsigned)f2bf(hi) << 16);
}

// ---------------- Kernel 1: fused prep + bf16 MFMA GEMM -> attn + rowAgg -----
// C[m,n] = sum_k W[m,k] * x[k,n] (per batch), raw fp32 inputs.
// B-tile: in-LDS transpose+cvt; A-fragments: per-lane global fp32->bf16.
__launch_bounds__(256)
__global__ void conv_gemm(const float* __restrict__ wsrc, const float* __restrict__ x,
                          const float* __restrict__ bias, ushort_t* __restrict__ attn,
                          float* __restrict__ rowAgg) {
    const int t = threadIdx.x;
    const int wv = t >> 6, lane = t & 63;
    const int q = lane >> 4, l15 = lane & 15;
    const int m0 = blockIdx.y * 64;
    const int mw = wv * 16;
    const int n_t = blockIdx.x * 64;
    const int b = n_t >> 10, nl0 = n_t & 1023;
    const int y0 = nl0 >> 5;

    __shared__ ushort_t Bs[64][264];     // [n][k] bf16, row stride 264 hw (33792 B)
    // Ct/red alias Bs after the MFMA loop (Bs dead then); 11264 + 5632 < 33792.
    ushort_t (*Ct)[2][44] = (ushort_t (*)[2][44])(&Bs[0][0]);
    float (*red)[11]      = (float (*)[11])((char*)(&Bs[0][0]) + 64 * 2 * 44 * 2);

    // ---- stage B: x[b][k][nl0..nl0+63] fp32 -> Bs[n][k] bf16 (transpose+cvt)
    // thread = (n-half, k-pair): packed b32 writes (k2,k2+1) -> <=2-way banks.
    {
        const int half = t >> 7;          // n-half (0: n 0-31, 1: n 32-63)
        const int kp = t & 127;           // k-pair index
        const int k2 = kp * 2;
        const float* xr0 = x + (size_t)b * (CIN * 1024) + (size_t)k2 * 1024 + nl0 + half * 32;
        const float* xr1 = xr0 + 1024;
        #pragma unroll
        for (int c = 0; c < 8; ++c) {
            const float4 u0 = *(const float4*)(xr0 + c * 4);
            const float4 u1 = *(const float4*)(xr1 + c * 4);
            const int nn = half * 32 + c * 4;
            *(unsigned*)&Bs[nn + 0][k2] = pk2(u0.x, u1.x);
            *(unsigned*)&Bs[nn + 1][k2] = pk2(u0.y, u1.y);
            *(unsigned*)&Bs[nn + 2][k2] = pk2(u0.z, u1.z);
            *(unsigned*)&Bs[nn + 3][k2] = pk2(u0.w, u1.w);
        }
    }
    __syncthreads();

    const float* aPf = wsrc + (size_t)(m0 + mw + l15) * 256 + q * 8;

    f32x4 acc[4] = {{0,0,0,0},{0,0,0,0},{0,0,0,0},{0,0,0,0}};
    #pragma unroll
    for (int k0 = 0; k0 < 256; k0 += 32) {
        const float4 af0 = *(const float4*)(aPf + k0);
        const float4 af1 = *(const float4*)(aPf + k0 + 4);
        s16x8 a;
        a[0] = (short)f2bf(af0.x); a[1] = (short)f2bf(af0.y);
        a[2] = (short)f2bf(af0.z); a[3] = (short)f2bf(af0.w);
        a[4] = (short)f2bf(af1.x); a[5] = (short)f2bf(af1.y);
        a[6] = (short)f2bf(af1.z); a[7] = (short)f2bf(af1.w);
        const int kk = k0 + q * 8;
        const s16x8 b0 = *(const s16x8*)&Bs[l15 +  0][kk];
        const s16x8 b1 = *(const s16x8*)&Bs[l15 + 16][kk];
        const s16x8 b2 = *(const s16x8*)&Bs[l15 + 32][kk];
        const s16x8 b3 = *(const s16x8*)&Bs[l15 + 48][kk];
        acc[0] = __builtin_amdgcn_mfma_f32_16x16x32_bf16(a, b0, acc[0], 0, 0, 0);
        acc[1] = __builtin_amdgcn_mfma_f32_16x16x32_bf16(a, b1, acc[1], 0, 0, 0);
        acc[2] = __builtin_amdgcn_mfma_f32_16x16x32_bf16(a, b2, acc[2], 0, 0, 0);
        acc[3] = __builtin_amdgcn_mfma_f32_16x16x32_bf16(a, b3, acc[3], 0, 0, 0);
    }
    __syncthreads();   // Bs dead; Ct/red aliasing begins

    float bb[4];
    #pragma unroll
    for (int r = 0; r < 4; ++r) bb[r] = bias[m0 + mw + q * 4 + r];
    #pragma unroll
    for (int j = 0; j < 4; ++j) {
        const int yy = j >> 1, xx = (j & 1) * 16 + l15;
        #pragma unroll
        for (int r = 0; r < 4; ++r)
            Ct[mw + q * 4 + r][yy][2 + xx] = f2bf(acc[j][r] + bb[r]);
    }
    #pragma unroll
    for (int it = 0; it < 2; ++it) {
        const int id = it * 256 + t;
        const int m = id >> 3, yy = (id >> 2) & 1, pos = id & 3;
        const int us = (pos == 0) ? 0 : (32 + 2 * pos);
        *(unsigned*)&Ct[m][yy][us] = 0u;
    }
    __syncthreads();

    ushort_t* pb = attn + ((size_t)(b * COUT + m0)) * PLANE;
    #pragma unroll
    for (int it = 0; it < 5; ++it) {
        const int id = it * 256 + t;
        const int m = id / 20, rem = id % 20, yy = rem / 10, s = rem % 10;
        const ull_t v = *(const ull_t*)&Ct[m][yy][s * 4];
        *(ull_t*)(pb + (size_t)m * PLANE + (y0 + yy + 2) * PW + s * 4) = v;
    }
    if (y0 == 0 || y0 == 30) {
        const int rowA = (y0 == 0) ? 0 : 34;
        #pragma unroll
        for (int it = 0; it < 5; ++it) {
            const int id = it * 256 + t;
            const int m = id / 20, rem = id % 20, yy = rem / 10, s = rem % 10;
            *(ull_t*)(pb + (size_t)m * PLANE + (rowA + yy) * PW + s * 4) = 0ull;
        }
    }

    if (t < 128) {
        const int gi = t >> 6, yy = (t >> 5) & 1, c = t & 31;
        const int m = gi * 32 + c;
        float lin = 0.f, sq = 0.f, e0 = 0.f, e1 = 0.f, e30 = 0.f, e31 = 0.f;
        #pragma unroll
        for (int u = 0; u < 9; ++u) {
            const ull_t vv = *(const ull_t*)&Ct[m][yy][u * 4];
            const unsigned lo = (unsigned)vv, hi = (unsigned)(vv >> 32);
            union { unsigned u; float f; } f0, f1, f2, f3;
            f0.u = lo << 16; f1.u = lo & 0xffff0000u;
            f2.u = hi << 16; f3.u = hi & 0xffff0000u;
            lin += (f0.f + f1.f) + (f2.f + f3.f);
            sq  += (f0.f * f0.f + f1.f * f1.f) + (f2.f * f2.f + f3.f * f3.f);
            if (u == 0) { e0 = f2.f; e1 = f3.f; }
            if (u == 8) { e30 = f0.f; e31 = f1.f; }
        }
        red[t][0] = lin; red[t][1] = sq;
        red[t][2] = e0;  red[t][3] = e0 * e0;
        red[t][4] = e1;  red[t][5] = e1 * e1;
        red[t][6] = e30; red[t][7] = e30 * e30;
        red[t][8] = e31; red[t][9] = e31 * e31;
    }
    __syncthreads();
    if (t < 40) {
        const int s = t % 10, gy = t / 10;
        const int gi = gy >> 1, yy = gy & 1;
        float sum = 0.f;
        #pragma unroll
        for (int c = 0; c < 32; ++c) sum += red[gi * 64 + yy * 32 + c][s];
        const int g = blockIdx.y * 2 + gi;
        rowAgg[(((size_t)b * G_ + g) * 32 + (y0 + yy)) * 10 + s] = sum;
    }
}

// ---------------- Kernel 2: tiny stats finalize ----------------
__launch_bounds__(64)
__global__ void gnfin(const float* __restrict__ rowAgg,
                      float* __restrict__ meanArr, float* __restrict__ rstdArr) {
    const int bg = blockIdx.x;
    const int t = threadIdx.x;
    __shared__ float rp[32][5], rp2[32][5];
    if (t < 32) {
        const float* a = rowAgg + ((size_t)bg * 32 + t) * 10;
        const float S = a[0], Sq = a[1];
        const float e0 = a[2], q0 = a[3], e1 = a[4], q1 = a[5];
        const float e30 = a[6], q30 = a[7], e31 = a[8], q31 = a[9];
        rp[t][0] = S - e30 - e31; rp[t][1] = S - e31; rp[t][2] = S;
        rp[t][3] = S - e0;        rp[t][4] = S - e0 - e1;
        rp2[t][0] = Sq - q30 - q31; rp2[t][1] = Sq - q31; rp2[t][2] = Sq;
        rp2[t][3] = Sq - q0;        rp2[t][4] = Sq - q0 - q1;
    }
    __syncthreads();
    if (t < 25) {
        const int kw = t % 5, kh = t / 5;
        float cs = 0.f, cs2 = 0.f;
        #pragma unroll
        for (int yy = 0; yy < 32; ++yy) { cs += rp[yy][kw]; cs2 += rp2[yy][kw]; }
        if (kh == 0)      { cs -= rp[30][kw] + rp[31][kw]; cs2 -= rp2[30][kw] + rp2[31][kw]; }
        else if (kh == 1) { cs -= rp[31][kw];              cs2 -= rp2[31][kw]; }
        else if (kh == 3) { cs -= rp[0][kw];               cs2 -= rp2[0][kw]; }
        else if (kh == 4) { cs -= rp[0][kw] + rp[1][kw];   cs2 -= rp2[0][kw] + rp2[1][kw]; }
        const float inv_n = 1.f / 32768.f;
        const float mean = cs * inv_n;
        const float var  = cs2 * inv_n - mean * mean;
        meanArr[bg * 25 + t] = mean;
        rstdArr[bg * 25 + t] = rsqrtf(var + EPS_);
    }
}

// ---------------- Kernel 3: local attention — 1-wave blocks, 1-row slabs,
// intra-wave channel split, double-buffered LDS, fence-only pipeline ----------
__launch_bounds__(64)
__global__ void local_attn(const ushort_t* __restrict__ attn,
                           const float* __restrict__ meanArr, const float* __restrict__ rstdArr,
                           const float* __restrict__ gn_w, const float* __restrict__ gn_b,
                           float* __restrict__ out) {
    const int blk = blockIdx.x;          // 2048 = b(8) x n(8) x row(32)
    const int b = blk >> 8;
    const int n = (blk >> 5) & 7;
    const int i0 = blk & 31;             // image row
    const int t = threadIdx.x;           // 64
    const int h = t >> 5;                // channel half
    const int j = t & 31;                // pixel column

    __shared__ float KB[2][2][208];      // [half][buf][5 rows x 40 + pad]
    __shared__ float QB[2][2][208];
    __shared__ float s_rq[25], s_mq[25], s_rk[25], s_ck[25], s_rv[25], s_cv[25];
    __shared__ float s_gw[96], s_gb[96];

    if (t < 25) {
        const int gk = (b * G_ + n * 3) * 25 + t;
        const float mK = meanArr[gk],      rK = rstdArr[gk];
        const float mQ = meanArr[gk + 25], rQ = rstdArr[gk + 25];
        const float mV = meanArr[gk + 50], rV = rstdArr[gk + 50];
        s_rk[t] = rK; s_ck[t] = mK * rK;
        s_rq[t] = rQ; s_mq[t] = mQ * rQ;
        s_rv[t] = rV; s_cv[t] = mV * rV;
    }
    s_gw[t] = gn_w[n * 96 + t];
    s_gb[t] = gn_b[n * 96 + t];
    if (t < 32) {
        s_gw[64 + t] = gn_w[n * 96 + 64 + t];
        s_gb[64 + t] = gn_b[n * 96 + 64 + t];
    }
    __syncthreads();

    float rq[25]; float cQ = 0.f;
    #pragma unroll
    for (int p = 0; p < 25; ++p) { rq[p] = s_rq[p]; cQ += s_mq[p]; }

    const ushort_t* regB = attn + (size_t)(b * COUT + n * 96) * PLANE + i0 * PW;
    const bool stg = (j < 25);
    const int eo1 = j * 4, eo2 = (j + 25) * 4;

    const ushort_t* baseK = regB + (size_t)(h * 16) * PLANE;
    const ushort_t* baseQ = regB + (size_t)(32 + h * 16) * PLANE;
    const ushort_t* baseV = regB + (size_t)(64 + h * 16) * PLANE;

    u16x4 nK1{0,0,0,0}, nK2{0,0,0,0}, nQ1{0,0,0,0}, nQ2{0,0,0,0};
    u16x4 fK1{0,0,0,0}, fK2{0,0,0,0}, fQ1{0,0,0,0}, fQ2{0,0,0,0};
    if (stg) {
        const u16x4 a1 = *(const u16x4*)(baseK + eo1), a2 = *(const u16x4*)(baseK + eo2);
        const u16x4 q1 = *(const u16x4*)(baseQ + eo1), q2 = *(const u16x4*)(baseQ + eo2);
        st4(&KB[h][0][eo1], a1); st4(&KB[h][0][eo2], a2);
        st4(&QB[h][0][eo1], q1); st4(&QB[h][0][eo2], q2);
        nK1 = *(const u16x4*)(baseK + PLANE + eo1); nK2 = *(const u16x4*)(baseK + PLANE + eo2);
        nQ1 = *(const u16x4*)(baseQ + PLANE + eo1); nQ2 = *(const u16x4*)(baseQ + PLANE + eo2);
        fK1 = *(const u16x4*)(baseK + 2 * (size_t)PLANE + eo1);
        fK2 = *(const u16x4*)(baseK + 2 * (size_t)PLANE + eo2);
        fQ1 = *(const u16x4*)(baseQ + 2 * (size_t)PLANE + eo1);
        fQ2 = *(const u16x4*)(baseQ + 2 * (size_t)PLANE + eo2);
    }
    LDS_FENCE();

    float sal[25];
    #pragma unroll
    for (int p = 0; p < 25; ++p) sal[p] = 0.f;
    float sumQ2 = 0.f, sumQB = 0.f;

    for (int cc = 0; cc < 16; ++cc) {
        const int buf = cc & 1;
        if (stg && cc < 15) {
            st4(&KB[h][buf ^ 1][eo1], nK1); st4(&KB[h][buf ^ 1][eo2], nK2);
            st4(&QB[h][buf ^ 1][eo1], nQ1); st4(&QB[h][buf ^ 1][eo2], nQ2);
            nK1 = fK1; nK2 = fK2; nQ1 = fQ1; nQ2 = fQ2;
            if (cc < 13) {
                fK1 = *(const u16x4*)(baseK + (size_t)(cc + 3) * PLANE + eo1);
                fK2 = *(const u16x4*)(baseK + (size_t)(cc + 3) * PLANE + eo2);
                fQ1 = *(const u16x4*)(baseQ + (size_t)(cc + 3) * PLANE + eo1);
                fQ2 = *(const u16x4*)(baseQ + (size_t)(cc + 3) * PLANE + eo2);
            } else if (cc == 13) {   // tail: prefetch V planes 0 and 1
                fK1 = *(const u16x4*)(baseV + eo1);
                fK2 = *(const u16x4*)(baseV + eo2);
                fQ1 = *(const u16x4*)(baseV + (size_t)PLANE + eo1);
                fQ2 = *(const u16x4*)(baseV + (size_t)PLANE + eo2);
            }
        }
        const int ch = h * 16 + cc;
        const float* qb = &QB[h][buf][j];
        const float* kb = &KB[h][buf][j];
        float qa0 = 0.f, qa1 = 0.f, qa2 = 0.f, qa3 = 0.f, qa4 = 0.f;
        #pragma unroll
        for (int kw = 0; kw < 5; ++kw) {
            qa0 += rq[0 * 5 + kw] * qb[0 * PW + kw];
            qa1 += rq[1 * 5 + kw] * qb[1 * PW + kw];
            qa2 += rq[2 * 5 + kw] * qb[2 * PW + kw];
            qa3 += rq[3 * 5 + kw] * qb[3 * PW + kw];
            qa4 += rq[4 * 5 + kw] * qb[4 * PW + kw];
        }
        const float qa = (qa0 + qa1) + (qa2 + qa3) + qa4;
        const float qk  = s_gw[32 + ch] * ((qa - cQ) * 0.04f) + s_gb[32 + ch];
        const float qk2 = qk * s_gw[ch];
        sumQ2 += qk2; sumQB += qk * s_gb[ch];
        #pragma unroll
        for (int kh = 0; kh < 5; ++kh)
            #pragma unroll
            for (int kw = 0; kw < 5; ++kw)
                sal[kh * 5 + kw] += qk2 * kb[kh * PW + kw];
        LDS_FENCE();
    }
    // after loop: nK = V plane 0, nQ = V plane 1 (rotated in via tail fetch)

    u16x4 vA1 = nQ1, vA2 = nQ2, vB1{0,0,0,0}, vB2{0,0,0,0};
    if (stg) {
        st4(&KB[h][0][eo1], nK1); st4(&KB[h][0][eo2], nK2);   // V0 -> buf0
        vB1 = *(const u16x4*)(baseV + 2 * (size_t)PLANE + eo1);
        vB2 = *(const u16x4*)(baseV + 2 * (size_t)PLANE + eo2);
    }

    // combine channel halves (lanes t <-> t^32)
    sumQ2 += __shfl_xor(sumQ2, 32);
    sumQB += __shfl_xor(sumQB, 32);
    #pragma unroll
    for (int p = 0; p < 25; ++p) sal[p] += __shfl_xor(sal[p], 32);

    #pragma unroll
    for (int p = 0; p < 25; ++p) sal[p] = s_rk[p] * sal[p] - s_ck[p] * sumQ2 + sumQB;

    const float scale = 0.17677669529663687f;  // 1/sqrt(32)
    float mmax = -3.4e38f;
    #pragma unroll
    for (int p = 0; p < 25; ++p) { sal[p] *= scale; mmax = fmaxf(mmax, sal[p]); }
    float ssum = 0.f;
    #pragma unroll
    for (int p = 0; p < 25; ++p) { sal[p] = __expf(sal[p] - mmax); ssum += sal[p]; }
    const float rs = 1.f / ssum;
    float cV2 = 0.f;
    #pragma unroll
    for (int p = 0; p < 25; ++p) {
        const float m = sal[p] * rs;
        sal[p] = m * s_rv[p];        // reuse sal as V-tap weights
        cV2 += m * s_cv[p];
    }
    LDS_FENCE();   // V0 staged above is visible

    for (int cc = 0; cc < 16; ++cc) {
        const int buf = cc & 1;
        if (stg && cc < 15) {
            st4(&KB[h][buf ^ 1][eo1], vA1); st4(&KB[h][buf ^ 1][eo2], vA2);
            vA1 = vB1; vA2 = vB2;
            if (cc < 13) {
                vB1 = *(const u16x4*)(baseV + (size_t)(cc + 3) * PLANE + eo1);
                vB2 = *(const u16x4*)(baseV + (size_t)(cc + 3) * PLANE + eo2);
            }
        }
        const int v = h * 16 + cc;
        const float* vb = &KB[h][buf][j];
        float a0 = 0.f, a1 = 0.f, a2 = 0.f, a3 = 0.f, a4 = 0.f;
        #pragma unroll
        for (int kw = 0; kw < 5; ++kw) {
            a0 += sal[0 * 5 + kw] * vb[0 * PW + kw];
            a1 += sal[1 * 5 + kw] * vb[1 * PW + kw];
            a2 += sal[2 * 5 + kw] * vb[2 * PW + kw];
            a3 += sal[3 * 5 + kw] * vb[3 * PW + kw];
            a4 += sal[4 * 5 + kw] * vb[4 * PW + kw];
        }
        const float acc = (a0 + a1) + (a2 + a3) + a4;
        out[((size_t)(b * 256 + n * 32 + v) * 32 + i0) * 32 + j] =
            s_gw[64 + v] * acc + (s_gb[64 + v] - s_gw[64 + v] * cV2);
        LDS_FENCE();
    }
}

extern "C" void kernel_launch(void* const* d_in, const int* in_sizes, int n_in,
                              void* d_out, int out_size, void* d_ws, size_t ws_size,
                              hipStream_t stream) {
    const float* x      = (const float*)d_in[0];
    const float* conv_w = (const float*)d_in[1];
    const float* conv_b = (const float*)d_in[2];
    const float* gn_w   = (const float*)d_in[3];
    const float* gn_b   = (const float*)d_in[4];
    float* out = (float*)d_out;

    // ws: attn bf16 padded | rowAgg f32 | mean | rstd
    ushort_t* attn    = (ushort_t*)d_ws;                    // 8,847,360 ushorts
    float*    rowAgg  = (float*)(attn + 8847360);           // 61,440
    float*    meanArr = rowAgg + 61440;                     // 4800
    float*    rstdArr = meanArr + 4800;                     // 4800

    conv_gemm<<<dim3(128, 12), 256, 0, stream>>>(conv_w, x, conv_b, attn, rowAgg);
    gnfin<<<192, 64, 0, stream>>>(rowAgg, meanArr, rstdArr);
    local_attn<<<2048, 64, 0, stream>>>(attn, meanArr, rstdArr, gn_w, gn_b, out);
}